// Round 1
// baseline (151.634 us; speedup 1.0000x reference)
//
#include <hip/hip_runtime.h>
#include <hip/hip_bf16.h>
#include <hip/hip_fp16.h>

// Problem constants: B=8, IN_C=64, H=W=32, NH=8, dkh=dvh=8, OUT_C=128.
// Inputs: float32 storage (verified R1/R2). Output: float32.
//
// R13->R14: k_out conv was LDS-issue-pipe bound (VALU conv: ~1400 ds_reads +
// 4608 FMA per thread; MfmaUtil 0, VALUBusy 18%). Rewritten as f16 implicit
// GEMM on MFMA 16x16x32_f16: M=8192 pos, N=64 oc, K=576 (9 taps x 64 ic).
// k_qkv og==0 blocks emit position-major f16 xT[b][p][64]; extra block 512
// emits wT[oc][tap*64+ic] f16. Conv block = 64 positions (2 image rows):
// 4-row x 34-col x 64-ic halo tile staged ONCE in LDS (XOR-swizzled), all 18
// K-steps read shifted views; B frags (18 x 16B/lane) live in registers.
// Epilogue transposes via LDS for coalesced float4 stores. k_attn unchanged.

// ---- workspace layout (float32 element offsets) ----
constexpr int QBUF  = 0;                       // [64 bn][1024][8] f32 (q pre-scaled)
constexpr int KVBUF = 524288;                  // [64 bn][1024][8] uint (f16x2 k|v)
constexpr int APRE  = KVBUF + 524288;          // [8][64][1024]
constexpr int XT    = APRE + 524288;           // f16 [8][1024][64] = 524288 halves
constexpr int WT    = XT + 262144;             // f16 [64][576] = 36864 halves
// total ~1.85M floats ~ 7.4 MB

typedef _Float16 h2 __attribute__((ext_vector_type(2)));
typedef _Float16 f16x8 __attribute__((ext_vector_type(8)));
typedef float f32x4 __attribute__((ext_vector_type(4)));

#if defined(__has_builtin)
#if __has_builtin(__builtin_amdgcn_fdot2)
#define HAVE_FDOT2 1
#endif
#endif

__device__ __forceinline__ float fdot2_acc(h2 a, h2 b, float c) {
#ifdef HAVE_FDOT2
    return __builtin_amdgcn_fdot2(a, b, c, false);
#else
    return c + (float)a[0] * (float)b[0] + (float)a[1] * (float)b[1];
#endif
}

__device__ __forceinline__ float dot8(float4 a, float4 b, const float* r) {
    return a.x*r[0] + a.y*r[1] + a.z*r[2] + a.w*r[3] +
           b.x*r[4] + b.y*r[5] + b.z*r[6] + b.w*r[7];
}

union KV16 { uint4 u; h2 h[4]; };
union PK16 { __half2 hh; unsigned int u; };
union F16V { uint4 u; f16x8 h; };

// ---------------------------------------------------------------------------
// Kernel 1: qkv 1x1 conv. grid = 8(b) x 4(pos chunk) x 16(out group of 12),
// plus block 512 = wT prep. og==0 blocks also write xT (f16, position-major).
// ---------------------------------------------------------------------------
__global__ __launch_bounds__(256) void k_qkv(
    const float* __restrict__ x,
    const float* __restrict__ wq,
    const float* __restrict__ bq,
    const float* __restrict__ wconv,
    float* __restrict__ qbuf,
    unsigned int* __restrict__ kvh,
    unsigned short* __restrict__ xt,
    __half* __restrict__ wt)
{
    int blk = blockIdx.x;
    int tid = threadIdx.x;

    if (blk >= 512) {                      // wT prep: wT[oc][tap*64+ic] f16
        for (int idx = tid; idx < 36864; idx += 256) {
            int ic = idx & 63, t2 = idx >> 6;   // t2 = oc*9 + tap
            int tap = t2 % 9, oc = t2 / 9;
            wt[idx] = __float2half_rn(wconv[oc * 576 + ic * 9 + tap]);
        }
        return;
    }

    __shared__ __align__(16) float4 wl4[192];   // 12 rows x 16 float4
    __shared__ float bl[12];

    int b = blk >> 6, rem = blk & 63, pc = rem >> 4, og = rem & 15;

    if (tid < 192) wl4[tid] = ((const float4*)(wq + og * 768))[tid];
    if (tid < 12)  bl[tid] = bq[og * 12 + tid];

    int p = pc * 256 + tid;                // 0..1023
    const float* xb = x + (b * 64) * 1024 + p;
    float xr[64];
    #pragma unroll
    for (int c = 0; c < 64; ++c) xr[c] = xb[c * 1024];

    __syncthreads();

    for (int pr = 0; pr < 6; ++pr) {       // channel pair (2 chains live)
        int oo = pr * 2;
        float accA = bl[oo], accB = bl[oo + 1];
        #pragma unroll
        for (int c4 = 0; c4 < 16; ++c4) {
            float4 wa = wl4[oo * 16 + c4];        // LDS broadcast
            float4 wb = wl4[(oo + 1) * 16 + c4];
            accA = fmaf(wa.x, xr[c4 * 4 + 0], accA);
            accA = fmaf(wa.y, xr[c4 * 4 + 1], accA);
            accA = fmaf(wa.z, xr[c4 * 4 + 2], accA);
            accA = fmaf(wa.w, xr[c4 * 4 + 3], accA);
            accB = fmaf(wb.x, xr[c4 * 4 + 0], accB);
            accB = fmaf(wb.y, xr[c4 * 4 + 1], accB);
            accB = fmaf(wb.z, xr[c4 * 4 + 2], accB);
            accB = fmaf(wb.w, xr[c4 * 4 + 3], accB);
        }
        int o = og * 12 + oo;              // even; pair never straddles q/k/v
        if (o < 64) {
            float2 qv = make_float2(accA * 0.35355339059327373f,
                                    accB * 0.35355339059327373f);
            *(float2*)(qbuf + ((b * 8 + (o >> 3)) * 1024 + p) * 8 + (o & 7)) = qv;
        } else {
            PK16 pk;
            pk.hh = __floats2half2_rn(accA, accB);
            int idx;
            if (o < 128) {
                int kk = o - 64;
                idx = ((b * 8 + (kk >> 3)) * 1024 + p) * 8 + ((kk & 7) >> 1);
            } else {
                int vv = o - 128;
                idx = ((b * 8 + (vv >> 3)) * 1024 + p) * 8 + 4 + ((vv & 7) >> 1);
            }
            kvh[idx] = pk.u;
        }
    }

    if (og == 0) {                         // xT: f16 [b][p][64 ic]
        unsigned int px[32];
        #pragma unroll
        for (int i = 0; i < 32; ++i) {
            PK16 pk;
            pk.hh = __floats2half2_rn(xr[2 * i], xr[2 * i + 1]);
            px[i] = pk.u;
        }
        uint4* dst = (uint4*)(xt + ((size_t)b * 1024 + p) * 64);
        #pragma unroll
        for (int j = 0; j < 8; ++j)
            dst[j] = make_uint4(px[4 * j], px[4 * j + 1], px[4 * j + 2], px[4 * j + 3]);
    }
}

// ---------------------------------------------------------------------------
// Kernel 2: attention. grid = 64(bn) x 8(query chunk of 128) = 512 blocks.
// (unchanged from R13)
// ---------------------------------------------------------------------------
__global__ __launch_bounds__(256) void k_attn(
    const float* __restrict__ qbuf,
    const unsigned int* __restrict__ kvh,
    const float* __restrict__ relw,
    const float* __restrict__ relh,
    float* __restrict__ apre)
{
    __shared__ __align__(16) float smem[12288];
    unsigned int* stageAll = (unsigned int*)(smem + 4096);

    int tid = threadIdx.x;
    int lane = tid & 63, quad = tid >> 6;
    int bn = blockIdx.x >> 3, qcv = blockIdx.x & 7;

    {
        int qi = tid & 127;
        int r0 = (tid >> 7) * 16;
        int iqf = qcv * 128 + qi;
        int wf = iqf & 31;
        const float* qpf = qbuf + (bn * 1024 + iqf) * 8;
        float4 fa = *(const float4*)qpf;
        float4 fb = *(const float4*)(qpf + 4);
        #pragma unroll
        for (int r = r0; r < r0 + 16; ++r)
            smem[r * 128 + qi] = dot8(fa, fb, relw + (r - wf + 31) * 8);
    }

    unsigned int* stg = stageAll + quad * 2048;
    {
        const uint4* src = (const uint4*)(kvh + (bn * 1024 + quad * 256) * 8);
        uint4* dst = (uint4*)stg;
        #pragma unroll
        for (int i = 0; i < 8; ++i)
            dst[i * 64 + lane] = src[i * 64 + lane];
    }

    int iq0 = qcv * 128 + lane, iq1 = iq0 + 64;
    int h0q = iq0 >> 5, h1q = iq1 >> 5;
    const float* qp0 = qbuf + (bn * 1024 + iq0) * 8;
    const float* qp1 = qbuf + (bn * 1024 + iq1) * 8;
    float4 q0a = *(const float4*)qp0, q0b = *(const float4*)(qp0 + 4);
    float4 q1a = *(const float4*)qp1, q1b = *(const float4*)(qp1 + 4);

    h2 qh0[4], qh1[4];
    qh0[0] = h2{(_Float16)q0a.x, (_Float16)q0a.y};
    qh0[1] = h2{(_Float16)q0a.z, (_Float16)q0a.w};
    qh0[2] = h2{(_Float16)q0b.x, (_Float16)q0b.y};
    qh0[3] = h2{(_Float16)q0b.z, (_Float16)q0b.w};
    qh1[0] = h2{(_Float16)q1a.x, (_Float16)q1a.y};
    qh1[1] = h2{(_Float16)q1a.z, (_Float16)q1a.w};
    qh1[2] = h2{(_Float16)q1b.x, (_Float16)q1b.y};
    qh1[3] = h2{(_Float16)q1b.z, (_Float16)q1b.w};

    float ah0[8], ah1[8];
    #pragma unroll
    for (int c = 0; c < 8; ++c) {
        int t = quad * 8 + c;
        ah0[c] = dot8(q0a, q0b, relh + (t - h0q + 31) * 8);
        ah1[c] = dot8(q1a, q1b, relh + (t - h1q + 31) * 8);
    }

    __syncthreads();

    h2 acc0[4] = {h2{0,0}, h2{0,0}, h2{0,0}, h2{0,0}};
    h2 acc1[4] = {h2{0,0}, h2{0,0}, h2{0,0}, h2{0,0}};
    float l0 = 0.f, l1 = 0.f;

    for (int w2 = 0; w2 < 32; ++w2) {
        float aw0 = smem[w2 * 128 + lane];
        float aw1 = smem[w2 * 128 + 64 + lane];
        const unsigned int* sk = stg + w2 * 8;
        #pragma unroll
        for (int c = 0; c < 8; ++c) {
            KV16 ku, vu;
            ku.u = *(const uint4*)(sk + c * 256);
            vu.u = *(const uint4*)(sk + c * 256 + 4);

            float s0 = aw0 + ah0[c];
            float s1 = aw1 + ah1[c];
            s0 = fdot2_acc(qh0[0], ku.h[0], s0);
            s0 = fdot2_acc(qh0[1], ku.h[1], s0);
            s0 = fdot2_acc(qh0[2], ku.h[2], s0);
            s0 = fdot2_acc(qh0[3], ku.h[3], s0);
            s1 = fdot2_acc(qh1[0], ku.h[0], s1);
            s1 = fdot2_acc(qh1[1], ku.h[1], s1);
            s1 = fdot2_acc(qh1[2], ku.h[2], s1);
            s1 = fdot2_acc(qh1[3], ku.h[3], s1);

            float pe0 = __expf(s0);
            float pe1 = __expf(s1);
            l0 += pe0; l1 += pe1;

            h2 p0 = h2{(_Float16)pe0, (_Float16)pe0};
            h2 p1 = h2{(_Float16)pe1, (_Float16)pe1};
            #pragma unroll
            for (int j = 0; j < 4; ++j) {
                acc0[j] += p0 * vu.h[j];
                acc1[j] += p1 * vu.h[j];
            }
        }
    }

    float f0[8], f1[8];
    #pragma unroll
    for (int j = 0; j < 4; ++j) {
        f0[2*j] = (float)acc0[j][0]; f0[2*j+1] = (float)acc0[j][1];
        f1[2*j] = (float)acc1[j][0]; f1[2*j+1] = (float)acc1[j][1];
    }

    __syncthreads();
    #pragma unroll
    for (int d = 0; d < 8; ++d) {
        smem[d * 256 + tid] = f0[d];
        smem[(9 + d) * 256 + tid] = f1[d];
    }
    smem[8 * 256 + tid] = l0;
    smem[17 * 256 + tid] = l1;
    __syncthreads();

    if (tid < 128) {
        int ln = tid & 63;
        int sb = (tid < 64) ? 0 : 9;
        float l = smem[(sb + 8) * 256 + ln]       + smem[(sb + 8) * 256 + ln + 64] +
                  smem[(sb + 8) * 256 + ln + 128] + smem[(sb + 8) * 256 + ln + 192];
        float inv = 1.0f / l;
        int b = bn >> 3, n = bn & 7;
        float* ap = apre + (b * 64 + n * 8) * 1024 + qcv * 128 + tid;
        #pragma unroll
        for (int d = 0; d < 8; ++d) {
            float av = smem[(sb + d) * 256 + ln]       + smem[(sb + d) * 256 + ln + 64] +
                       smem[(sb + d) * 256 + ln + 128] + smem[(sb + d) * 256 + ln + 192];
            ap[d * 1024] = av * inv;
        }
    }
}

// ---------------------------------------------------------------------------
// Kernel 3: fused output. grid = 384 blocks:
//   blk < 128: 3x3 conv via MFMA implicit GEMM. b=blk>>4, r0=(blk&15)*2.
//     M-tile = 64 positions (2 image rows), N = 64 oc, K = 576.
//     A: halo tile [4 rows][34 cols][64 ic] f16 in LDS, XOR-swizzled
//     (16B slot within each 128B position block ^= col&7) so stride-128B
//     fragment reads distribute evenly over banks. Staged ONCE; 18 K-steps
//     (tap, ic-half) read shifted views. B: wave w owns oc n0=w*16; 18
//     frags x 16B/lane loaded once from wT (L2). 72 MFMA/wave. Epilogue:
//     transpose through LDS [64 m][65] -> coalesced float4 stores + bias.
//   blk >= 128: attn 1x1 proj (unchanged logic).
// ---------------------------------------------------------------------------
__global__ __launch_bounds__(256) void k_out(
    const unsigned short* __restrict__ xt,
    const unsigned short* __restrict__ wt,
    const float* __restrict__ bconv,
    const float* __restrict__ wattn,
    const float* __restrict__ battn,
    const float* __restrict__ apre,
    float* __restrict__ out)
{
    __shared__ __align__(16) float smem[4352];   // conv: 17408B A-tile, then 64x65 f32 out-transpose
    int blk = blockIdx.x;
    int tid = threadIdx.x;

    if (blk < 128) {
        int b = blk >> 4;
        int r0 = (blk & 15) * 2;           // image rows r0, r0+1
        int p0 = r0 * 32;
        int lane = tid & 63, wv = tid >> 6;
        int lr = lane & 15, lk = lane >> 4;
        int n0 = wv * 16;                  // this wave's oc base

        // ---- B fragments: B[k=lk*8..+7][n=n0+lr], 18 K-steps, from wT[oc][k]
        F16V bw[18];
        {
            const uint4* wp = (const uint4*)(wt + (n0 + lr) * 576 + lk * 8);
            #pragma unroll
            for (int kk = 0; kk < 18; ++kk) bw[kk].u = wp[kk * 4];   // +32 halves per step
        }

        // ---- stage A halo tile: 4 rows x 34 cols x 8 slots of 16B ----
        unsigned char* ats = (unsigned char*)smem;
        {
            const uint4* xsrc = (const uint4*)xt + b * 8192;   // [1024 pos][8 slots]
            #pragma unroll
            for (int it = 0; it < 5; ++it) {
                int chunk = tid + it * 256;
                if (chunk < 1088) {
                    int s = chunk & 7, cpos = chunk >> 3;
                    int sr = cpos / 34, sc = cpos - sr * 34;
                    int ir = r0 - 1 + sr, icc = sc - 1;
                    uint4 v = make_uint4(0u, 0u, 0u, 0u);
                    if (((unsigned)ir < 32u) && ((unsigned)icc < 32u))
                        v = xsrc[(ir * 32 + icc) * 8 + s];
                    int db = ((sr * 34 + sc) * 128 + s * 16) ^ ((sc & 7) << 4);
                    *(uint4*)(ats + db) = v;
                }
            }
        }
        __syncthreads();

        f32x4 acc[4];
        #pragma unroll
        for (int mb = 0; mb < 4; ++mb) acc[mb] = f32x4{0.f, 0.f, 0.f, 0.f};

        // ---- K loop: kk = tap*2 + ic-half; A[m][k]=x[r+dr-1][c+dc-1][ic]
        #pragma unroll
        for (int kk = 0; kk < 18; ++kk) {
            const int tap = kk >> 1, h = kk & 1;
            const int dr = tap / 3, dc = tap - dr * 3;     // compile-time
            #pragma unroll
            for (int mb = 0; mb < 4; ++mb) {
                int m = mb * 16 + lr;                      // A row = lane&15
                int sr = (m >> 5) + dr, sc = (m & 31) + dc;
                int db = ((sr * 34 + sc) * 128 + h * 64 + lk * 16) ^ ((sc & 7) << 4);
                F16V av;
                av.u = *(const uint4*)(ats + db);
                acc[mb] = __builtin_amdgcn_mfma_f32_16x16x32_f16(av.h, bw[kk].h, acc[mb], 0, 0, 0);
            }
        }

        // ---- epilogue: D[row=lk*4+r + mb*16][col=n0+lr] -> LDS -> coalesced
        __syncthreads();                   // A-tile reads done; reuse smem
        #pragma unroll
        for (int mb = 0; mb < 4; ++mb) {
            #pragma unroll
            for (int r = 0; r < 4; ++r)
                smem[(mb * 16 + lk * 4 + r) * 65 + n0 + lr] = acc[mb][r];
        }
        __syncthreads();

        int oc = tid >> 2, pq = tid & 3;
        float bia = bconv[oc];
        float* op = out + ((b * 128 + oc) * 1024) + p0 + pq * 16;
        #pragma unroll
        for (int j4 = 0; j4 < 4; ++j4) {
            int mloc = pq * 16 + j4 * 4;
            float4 o4;
            o4.x = smem[(mloc + 0) * 65 + oc] + bia;
            o4.y = smem[(mloc + 1) * 65 + oc] + bia;
            o4.z = smem[(mloc + 2) * 65 + oc] + bia;
            o4.w = smem[(mloc + 3) * 65 + oc] + bia;
            *(float4*)(op + j4 * 4) = o4;
        }
    } else {
        int pb = blk - 128;
        int b = pb >> 5, rem = pb & 31, rg = rem >> 3, og = rem & 7;
        int o0 = og * 8;
        float* wl = smem;                  // [64 c][8 g]
        for (int i = tid; i < 512; i += 256) {
            int g = i & 7, c = i >> 3;
            wl[c * 8 + g] = wattn[(o0 + g) * 64 + c];
        }
        if (tid < 8) smem[512 + tid] = battn[o0 + tid];
        __syncthreads();

        int p = rg * 256 + tid;
        float acc[8] = {0,0,0,0,0,0,0,0};
        const float* ap = apre + b * 65536 + p;
        #pragma unroll 4
        for (int c = 0; c < 64; ++c) {
            float xv = ap[c * 1024];
            const float4* wv4 = (const float4*)(wl + c * 8);
            float4 wa = wv4[0], wb = wv4[1];  // broadcast
            acc[0] = fmaf(wa.x, xv, acc[0]); acc[1] = fmaf(wa.y, xv, acc[1]);
            acc[2] = fmaf(wa.z, xv, acc[2]); acc[3] = fmaf(wa.w, xv, acc[3]);
            acc[4] = fmaf(wb.x, xv, acc[4]); acc[5] = fmaf(wb.y, xv, acc[5]);
            acc[6] = fmaf(wb.z, xv, acc[6]); acc[7] = fmaf(wb.w, xv, acc[7]);
        }
        #pragma unroll
        for (int g = 0; g < 8; ++g)
            out[(b * 128 + 64 + o0 + g) * 1024 + p] = acc[g] + smem[512 + g];
    }
}

// ---------------------------------------------------------------------------
extern "C" void kernel_launch(void* const* d_in, const int* in_sizes, int n_in,
                              void* d_out, int out_size, void* d_ws, size_t ws_size,
                              hipStream_t stream)
{
    float* ws = (float*)d_ws;
    float* out = (float*)d_out;
    const float* x      = (const float*)d_in[0];
    const float* conv_w = (const float*)d_in[1];
    const float* conv_b = (const float*)d_in[2];
    const float* qkv_w  = (const float*)d_in[3];
    const float* qkv_b  = (const float*)d_in[4];
    const float* attn_w = (const float*)d_in[5];
    const float* attn_b = (const float*)d_in[6];
    const float* rel_w  = (const float*)d_in[7];
    const float* rel_h  = (const float*)d_in[8];

    k_qkv<<<513, 256, 0, stream>>>(
        x, qkv_w, qkv_b, conv_w,
        ws + QBUF, (unsigned int*)(ws + KVBUF),
        (unsigned short*)(ws + XT), (__half*)(ws + WT));
    k_attn<<<512, 256, 0, stream>>>(
        ws + QBUF, (const unsigned int*)(ws + KVBUF), rel_w, rel_h, ws + APRE);
    k_out<<<384, 256, 0, stream>>>(
        (const unsigned short*)(ws + XT), (const unsigned short*)(ws + WT),
        conv_b, attn_w, attn_b, ws + APRE, out);
}

// Round 3
// 120.845 us; speedup vs baseline: 1.2548x; 1.2548x over previous
//
#include <hip/hip_runtime.h>
#include <hip/hip_bf16.h>
#include <hip/hip_fp16.h>

// Problem constants: B=8, IN_C=64, H=W=32, NH=8, dkh=dvh=8, OUT_C=128.
//
// R14->R16:
// (1) k_qkv wT-prep straggler (1 block, 144 serial strided loads ~40us of
//     idle-GPU tail; occupancy 3.8%/VALU 7% signature) -> 16 blocks,
//     coalesced src-linear reads, 9 unrolled iters/thread.
// (2) k_attn rewritten on MFMA. No-max softmax => pure accumulation:
//     acc1 = mfma_f32_16x16x32_f16(K_frag, Q_frag)   (d padded 8->32, Q zeroed)
//     p    = exp(acc1 + AW[q][key&31] + AH[q][key>>5])  (pre-shifted tables)
//     acc2 = mfma_f32_16x16x16f16(Vt_frag, p)        (V transposed in LDS;
//            row 8 of Vt = ones => acc2 row 8 = softmax denominator, free)
//     Block = (bn, 128 queries), 4 waves x 32 q, all 1024 keys staged once.
// (3) k_out proj: unroll 4 -> 16 (deeper load pipelining on apre).
// R15->R16: fixed builtin spelling (mfma_f32_16x16x16f16 — compiler-confirmed).

// ---- workspace layout (float32 element offsets) ----
constexpr int QBUF  = 0;                       // [64 bn][1024][8] f32 (q pre-scaled)
constexpr int KVBUF = 524288;                  // [64 bn][1024][8] uint (f16x2 k|v)
constexpr int APRE  = KVBUF + 524288;          // [8][64][1024]
constexpr int XT    = APRE + 524288;           // f16 [8][1024][64] = 524288 halves
constexpr int WT    = XT + 262144;             // f16 [64][576] = 36864 halves

typedef _Float16 h2 __attribute__((ext_vector_type(2)));
typedef _Float16 f16x4 __attribute__((ext_vector_type(4)));
typedef _Float16 f16x8 __attribute__((ext_vector_type(8)));
typedef float f32x4 __attribute__((ext_vector_type(4)));

#if defined(__has_builtin)
#if __has_builtin(__builtin_amdgcn_fdot2)
#define HAVE_FDOT2 1
#endif
#endif

__device__ __forceinline__ float fdot2_acc(h2 a, h2 b, float c) {
#ifdef HAVE_FDOT2
    return __builtin_amdgcn_fdot2(a, b, c, false);
#else
    return c + (float)a[0] * (float)b[0] + (float)a[1] * (float)b[1];
#endif
}

__device__ __forceinline__ float dot8(float4 a, float4 b, const float* r) {
    return a.x*r[0] + a.y*r[1] + a.z*r[2] + a.w*r[3] +
           b.x*r[4] + b.y*r[5] + b.z*r[6] + b.w*r[7];
}

__device__ __forceinline__ f32x4 mfma16x16x32f16(f16x8 a, f16x8 b, f32x4 c) {
    return __builtin_amdgcn_mfma_f32_16x16x32_f16(a, b, c, 0, 0, 0);
}

__device__ __forceinline__ f32x4 mfma16x16x16f16(f16x4 a, f16x4 b, f32x4 c) {
    return __builtin_amdgcn_mfma_f32_16x16x16f16(a, b, c, 0, 0, 0);
}

union KV16 { uint4 u; h2 h[4]; };
union PK16 { __half2 hh; unsigned int u; };
union F16V { uint4 u; f16x8 h; };
union F16V4 { uint2 u; f16x4 h; };

// ---------------------------------------------------------------------------
// Kernel 1: qkv 1x1 conv. grid = 512 main blocks + 16 wT-prep blocks.
// og==0 blocks also write xT (f16, position-major).
// ---------------------------------------------------------------------------
__global__ __launch_bounds__(256) void k_qkv(
    const float* __restrict__ x,
    const float* __restrict__ wq,
    const float* __restrict__ bq,
    const float* __restrict__ wconv,
    float* __restrict__ qbuf,
    unsigned int* __restrict__ kvh,
    unsigned short* __restrict__ xt,
    __half* __restrict__ wt)
{
    int blk = blockIdx.x;
    int tid = threadIdx.x;

    if (blk >= 512) {                      // wT prep: 16 blocks x 4 oc each
        int oc0 = (blk - 512) * 4;
        const float* src = wconv + oc0 * 576;   // coalesced linear reads
        #pragma unroll
        for (int j = 0; j < 9; ++j) {
            int local = tid + j * 256;     // 0..2303 (= 4*576)
            float v = src[local];
            int ocr = local / 576, rem = local % 576;
            int ic = rem / 9, tap = rem % 9;
            wt[(oc0 + ocr) * 576 + tap * 64 + ic] = __float2half_rn(v);
        }
        return;
    }

    __shared__ __align__(16) float4 wl4[192];   // 12 rows x 16 float4
    __shared__ float bl[12];

    int b = blk >> 6, rem = blk & 63, pc = rem >> 4, og = rem & 15;

    if (tid < 192) wl4[tid] = ((const float4*)(wq + og * 768))[tid];
    if (tid < 12)  bl[tid] = bq[og * 12 + tid];

    int p = pc * 256 + tid;                // 0..1023
    const float* xb = x + (b * 64) * 1024 + p;
    float xr[64];
    #pragma unroll
    for (int c = 0; c < 64; ++c) xr[c] = xb[c * 1024];

    __syncthreads();

    for (int pr = 0; pr < 6; ++pr) {       // channel pair (2 chains live)
        int oo = pr * 2;
        float accA = bl[oo], accB = bl[oo + 1];
        #pragma unroll
        for (int c4 = 0; c4 < 16; ++c4) {
            float4 wa = wl4[oo * 16 + c4];        // LDS broadcast
            float4 wb = wl4[(oo + 1) * 16 + c4];
            accA = fmaf(wa.x, xr[c4 * 4 + 0], accA);
            accA = fmaf(wa.y, xr[c4 * 4 + 1], accA);
            accA = fmaf(wa.z, xr[c4 * 4 + 2], accA);
            accA = fmaf(wa.w, xr[c4 * 4 + 3], accA);
            accB = fmaf(wb.x, xr[c4 * 4 + 0], accB);
            accB = fmaf(wb.y, xr[c4 * 4 + 1], accB);
            accB = fmaf(wb.z, xr[c4 * 4 + 2], accB);
            accB = fmaf(wb.w, xr[c4 * 4 + 3], accB);
        }
        int o = og * 12 + oo;              // even; pair never straddles q/k/v
        if (o < 64) {
            float2 qv = make_float2(accA * 0.35355339059327373f,
                                    accB * 0.35355339059327373f);
            *(float2*)(qbuf + ((b * 8 + (o >> 3)) * 1024 + p) * 8 + (o & 7)) = qv;
        } else {
            PK16 pk;
            pk.hh = __floats2half2_rn(accA, accB);
            int idx;
            if (o < 128) {
                int kk = o - 64;
                idx = ((b * 8 + (kk >> 3)) * 1024 + p) * 8 + ((kk & 7) >> 1);
            } else {
                int vv = o - 128;
                idx = ((b * 8 + (vv >> 3)) * 1024 + p) * 8 + 4 + ((vv & 7) >> 1);
            }
            kvh[idx] = pk.u;
        }
    }

    if (og == 0) {                         // xT: f16 [b][p][64 ic]
        unsigned int px[32];
        #pragma unroll
        for (int i = 0; i < 32; ++i) {
            PK16 pk;
            pk.hh = __floats2half2_rn(xr[2 * i], xr[2 * i + 1]);
            px[i] = pk.u;
        }
        uint4* dst = (uint4*)(xt + ((size_t)b * 1024 + p) * 64);
        #pragma unroll
        for (int j = 0; j < 8; ++j)
            dst[j] = make_uint4(px[4 * j], px[4 * j + 1], px[4 * j + 2], px[4 * j + 3]);
    }
}

// ---------------------------------------------------------------------------
// Kernel 2: attention via MFMA. grid = 64(bn) x 8(query chunk of 128) = 512.
// 4 waves x 32 queries; all 1024 keys staged once:
//   Kl [1024][8]h linear, Vt [9][1032]h transposed (row 8 = ones -> l-sum),
//   AWS [128][36]f32 / AHS [128][36]h: rel-bias tables PRE-SHIFTED by query
//   position so lookups are aligned vector reads (index = key&31 / key>>5).
// Per key-tile kt (16 keys): 1 b128 K-frag + 1 b64 Vt-frag + per q-tile
// {QK mfma(x32, d-padded), bias b128+u16, 4 exp, PV mfma(x16)}.
// Q-frag zeroed in lanes 16..63 kills the d 8..31 padding; Vt garbage rows
// 9..15 (reads alias the Kl region: finite f16) only feed discarded rows.
// ---------------------------------------------------------------------------
__global__ __launch_bounds__(256) void k_attn(
    const float* __restrict__ qbuf,
    const unsigned int* __restrict__ kvh,
    const float* __restrict__ relw,
    const float* __restrict__ relh,
    float* __restrict__ apre)
{
    __shared__ __align__(16) unsigned char smem[62608];
    unsigned short* Vt  = (unsigned short*)smem;            // [9][1032] halves
    unsigned short* Kl  = (unsigned short*)(smem + 18576);  // [1024][8] halves
    float*          AWS = (float*)(smem + 34960);           // [128][36] f32
    _Float16*       AHS = (_Float16*)(smem + 53392);        // [128][36] f16

    int tid = threadIdx.x;
    int lane = tid & 63, wv = tid >> 6;
    int bn = blockIdx.x >> 3, qc = blockIdx.x & 7;
    int b = bn >> 3, nh = bn & 7;

    // ---- stage K (linear) + V (transposed pairs) ----
    {
        const uint4* kvsrc = (const uint4*)kvh + bn * 2048;  // [pos*2 + {k,v}]
        int p0 = tid * 4;
        #pragma unroll
        for (int pp = 0; pp < 2; ++pp) {
            int pa = p0 + pp * 2;
            uint4 ka = kvsrc[pa * 2 + 0], va = kvsrc[pa * 2 + 1];
            uint4 kb = kvsrc[pa * 2 + 2], vb = kvsrc[pa * 2 + 3];
            *(uint4*)(Kl + pa * 8) = ka;
            *(uint4*)(Kl + pa * 8 + 8) = kb;
            const unsigned short* ha = (const unsigned short*)&va;
            const unsigned short* hb = (const unsigned short*)&vb;
            #pragma unroll
            for (int dv = 0; dv < 8; ++dv) {
                unsigned int pk = (unsigned int)ha[dv] | ((unsigned int)hb[dv] << 16);
                *(unsigned int*)(Vt + dv * 1032 + pa) = pk;
            }
        }
        // ones row (dv==8): acc2 row 8 accumulates sum(P) = denominator
        *(unsigned long long*)(Vt + 8 * 1032 + tid * 4) = 0x3C003C003C003C00ull;
    }

    // ---- pre-shifted bias tables ----
    {
        int qloc = tid >> 1, hh = (tid & 1) * 16;
        int q = qc * 128 + qloc;
        const float* qp = qbuf + (bn * 1024 + q) * 8;
        float4 qa = *(const float4*)qp, qb2 = *(const float4*)(qp + 4);
        int wq = q & 31, hq = q >> 5;
        #pragma unroll
        for (int m = 0; m < 16; ++m)
            AWS[qloc * 36 + hh + m] = dot8(qa, qb2, relw + (hh + m + 31 - wq) * 8);
        #pragma unroll
        for (int m = 0; m < 16; ++m)
            AHS[qloc * 36 + hh + m] =
                (_Float16)dot8(qa, qb2, relh + (hh + m + 31 - hq) * 8);
    }

    // ---- per-wave Q fragments (2 q-tiles of 16 queries) ----
    int r = lane & 15, g = lane >> 4;
    int qrow0 = wv * 32;
    f16x8 qf[2];
    #pragma unroll
    for (int qt = 0; qt < 2; ++qt) {
        f16x8 v = {0, 0, 0, 0, 0, 0, 0, 0};
        if (g == 0) {
            const float* qp = qbuf + (bn * 1024 + qc * 128 + qrow0 + qt * 16 + r) * 8;
            float4 a = *(const float4*)qp;
            float4 c = *(const float4*)(qp + 4);
            v[0] = (_Float16)a.x; v[1] = (_Float16)a.y;
            v[2] = (_Float16)a.z; v[3] = (_Float16)a.w;
            v[4] = (_Float16)c.x; v[5] = (_Float16)c.y;
            v[6] = (_Float16)c.z; v[7] = (_Float16)c.w;
        }
        qf[qt] = v;
    }

    __syncthreads();

    f32x4 acc2[2] = {{0.f, 0.f, 0.f, 0.f}, {0.f, 0.f, 0.f, 0.f}};

    #pragma unroll 2
    for (int kt = 0; kt < 64; ++kt) {
        F16V kf;  kf.u = *(const uint4*)(Kl + (kt * 16 + r) * 8);       // all groups broadcast row r
        F16V4 vt; vt.u = *(const uint2*)(Vt + r * 1032 + kt * 16 + g * 4);
        int m0 = ((kt & 1) << 4) + g * 4;
        int hb = kt >> 1;
        #pragma unroll
        for (int qt = 0; qt < 2; ++qt) {
            int qrow = qrow0 + qt * 16 + r;
            f32x4 a1 = mfma16x16x32f16(kf.h, qf[qt], (f32x4){0.f, 0.f, 0.f, 0.f});
            float4 aw = *(const float4*)(AWS + qrow * 36 + m0);
            float ah = (float)AHS[qrow * 36 + hb];
            float e0 = __expf(a1[0] + aw.x + ah);
            float e1 = __expf(a1[1] + aw.y + ah);
            float e2 = __expf(a1[2] + aw.z + ah);
            float e3 = __expf(a1[3] + aw.w + ah);
            f16x4 pf;
            pf[0] = (_Float16)e0; pf[1] = (_Float16)e1;
            pf[2] = (_Float16)e2; pf[3] = (_Float16)e3;
            acc2[qt] = mfma16x16x16f16(vt.h, pf, acc2[qt]);
        }
    }

    // ---- epilogue: l = acc2 row 8 (lane 32+r, elem 0); scale + store ----
    #pragma unroll
    for (int qt = 0; qt < 2; ++qt) {
        float lsum = __shfl(acc2[qt][0], 32 + r, 64);
        float inv = 1.0f / lsum;
        if (g < 2) {
            int qglob = qc * 128 + qrow0 + qt * 16 + r;
            float* ap = apre + (b * 64 + nh * 8 + g * 4) * 1024 + qglob;
            ap[0]    = acc2[qt][0] * inv;
            ap[1024] = acc2[qt][1] * inv;
            ap[2048] = acc2[qt][2] * inv;
            ap[3072] = acc2[qt][3] * inv;
        }
    }
}

// ---------------------------------------------------------------------------
// Kernel 3: fused output. grid = 384 blocks:
//   blk < 128: 3x3 conv via MFMA implicit GEMM (unchanged from R14).
//   blk >= 128: attn 1x1 proj (unroll 4 -> 16 for deeper load pipelining).
// ---------------------------------------------------------------------------
__global__ __launch_bounds__(256) void k_out(
    const unsigned short* __restrict__ xt,
    const unsigned short* __restrict__ wt,
    const float* __restrict__ bconv,
    const float* __restrict__ wattn,
    const float* __restrict__ battn,
    const float* __restrict__ apre,
    float* __restrict__ out)
{
    __shared__ __align__(16) float smem[4352];
    int blk = blockIdx.x;
    int tid = threadIdx.x;

    if (blk < 128) {
        int b = blk >> 4;
        int r0 = (blk & 15) * 2;           // image rows r0, r0+1
        int p0 = r0 * 32;
        int lane = tid & 63, wv = tid >> 6;
        int lr = lane & 15, lk = lane >> 4;
        int n0 = wv * 16;                  // this wave's oc base

        // ---- B fragments: B[k=lk*8..+7][n=n0+lr], 18 K-steps, from wT[oc][k]
        F16V bw[18];
        {
            const uint4* wp = (const uint4*)(wt + (n0 + lr) * 576 + lk * 8);
            #pragma unroll
            for (int kk = 0; kk < 18; ++kk) bw[kk].u = wp[kk * 4];
        }

        // ---- stage A halo tile: 4 rows x 34 cols x 8 slots of 16B ----
        unsigned char* ats = (unsigned char*)smem;
        {
            const uint4* xsrc = (const uint4*)xt + b * 8192;   // [1024 pos][8 slots]
            #pragma unroll
            for (int it = 0; it < 5; ++it) {
                int chunk = tid + it * 256;
                if (chunk < 1088) {
                    int s = chunk & 7, cpos = chunk >> 3;
                    int sr = cpos / 34, sc = cpos - sr * 34;
                    int ir = r0 - 1 + sr, icc = sc - 1;
                    uint4 v = make_uint4(0u, 0u, 0u, 0u);
                    if (((unsigned)ir < 32u) && ((unsigned)icc < 32u))
                        v = xsrc[(ir * 32 + icc) * 8 + s];
                    int db = ((sr * 34 + sc) * 128 + s * 16) ^ ((sc & 7) << 4);
                    *(uint4*)(ats + db) = v;
                }
            }
        }
        __syncthreads();

        f32x4 acc[4];
        #pragma unroll
        for (int mb = 0; mb < 4; ++mb) acc[mb] = f32x4{0.f, 0.f, 0.f, 0.f};

        // ---- K loop: kk = tap*2 + ic-half; A[m][k]=x[r+dr-1][c+dc-1][ic]
        #pragma unroll
        for (int kk = 0; kk < 18; ++kk) {
            const int tap = kk >> 1, h = kk & 1;
            const int dr = tap / 3, dc = tap - dr * 3;     // compile-time
            #pragma unroll
            for (int mb = 0; mb < 4; ++mb) {
                int m = mb * 16 + lr;                      // A row = lane&15
                int sr = (m >> 5) + dr, sc = (m & 31) + dc;
                int db = ((sr * 34 + sc) * 128 + h * 64 + lk * 16) ^ ((sc & 7) << 4);
                F16V av;
                av.u = *(const uint4*)(ats + db);
                acc[mb] = __builtin_amdgcn_mfma_f32_16x16x32_f16(av.h, bw[kk].h, acc[mb], 0, 0, 0);
            }
        }

        // ---- epilogue: D[row=lk*4+r + mb*16][col=n0+lr] -> LDS -> coalesced
        __syncthreads();                   // A-tile reads done; reuse smem
        #pragma unroll
        for (int mb = 0; mb < 4; ++mb) {
            #pragma unroll
            for (int rr = 0; rr < 4; ++rr)
                smem[(mb * 16 + lk * 4 + rr) * 65 + n0 + lr] = acc[mb][rr];
        }
        __syncthreads();

        int oc = tid >> 2, pq = tid & 3;
        float bia = bconv[oc];
        float* op = out + ((b * 128 + oc) * 1024) + p0 + pq * 16;
        #pragma unroll
        for (int j4 = 0; j4 < 4; ++j4) {
            int mloc = pq * 16 + j4 * 4;
            float4 o4;
            o4.x = smem[(mloc + 0) * 65 + oc] + bia;
            o4.y = smem[(mloc + 1) * 65 + oc] + bia;
            o4.z = smem[(mloc + 2) * 65 + oc] + bia;
            o4.w = smem[(mloc + 3) * 65 + oc] + bia;
            *(float4*)(op + j4 * 4) = o4;
        }
    } else {
        int pb = blk - 128;
        int b = pb >> 5, rem = pb & 31, rg = rem >> 3, og = rem & 7;
        int o0 = og * 8;
        float* wl = smem;                  // [64 c][8 g]
        for (int i = tid; i < 512; i += 256) {
            int g = i & 7, c = i >> 3;
            wl[c * 8 + g] = wattn[(o0 + g) * 64 + c];
        }
        if (tid < 8) smem[512 + tid] = battn[o0 + tid];
        __syncthreads();

        int p = rg * 256 + tid;
        float acc[8] = {0, 0, 0, 0, 0, 0, 0, 0};
        const float* ap = apre + b * 65536 + p;
        #pragma unroll 16
        for (int c = 0; c < 64; ++c) {
            float xv = ap[c * 1024];
            const float4* wv4 = (const float4*)(wl + c * 8);
            float4 wa = wv4[0], wb = wv4[1];  // broadcast
            acc[0] = fmaf(wa.x, xv, acc[0]); acc[1] = fmaf(wa.y, xv, acc[1]);
            acc[2] = fmaf(wa.z, xv, acc[2]); acc[3] = fmaf(wa.w, xv, acc[3]);
            acc[4] = fmaf(wb.x, xv, acc[4]); acc[5] = fmaf(wb.y, xv, acc[5]);
            acc[6] = fmaf(wb.z, xv, acc[6]); acc[7] = fmaf(wb.w, xv, acc[7]);
        }
        #pragma unroll
        for (int g = 0; g < 8; ++g)
            out[(b * 128 + 64 + o0 + g) * 1024 + p] = acc[g] + smem[512 + g];
    }
}

// ---------------------------------------------------------------------------
extern "C" void kernel_launch(void* const* d_in, const int* in_sizes, int n_in,
                              void* d_out, int out_size, void* d_ws, size_t ws_size,
                              hipStream_t stream)
{
    float* ws = (float*)d_ws;
    float* out = (float*)d_out;
    const float* x      = (const float*)d_in[0];
    const float* conv_w = (const float*)d_in[1];
    const float* conv_b = (const float*)d_in[2];
    const float* qkv_w  = (const float*)d_in[3];
    const float* qkv_b  = (const float*)d_in[4];
    const float* attn_w = (const float*)d_in[5];
    const float* attn_b = (const float*)d_in[6];
    const float* rel_w  = (const float*)d_in[7];
    const float* rel_h  = (const float*)d_in[8];

    k_qkv<<<528, 256, 0, stream>>>(
        x, qkv_w, qkv_b, conv_w,
        ws + QBUF, (unsigned int*)(ws + KVBUF),
        (unsigned short*)(ws + XT), (__half*)(ws + WT));
    k_attn<<<512, 256, 0, stream>>>(
        ws + QBUF, (const unsigned int*)(ws + KVBUF), rel_w, rel_h, ws + APRE);
    k_out<<<384, 256, 0, stream>>>(
        (const unsigned short*)(ws + XT), (const unsigned short*)(ws + WT),
        conv_b, attn_w, attn_b, ws + APRE, out);
}

// Round 5
// 117.428 us; speedup vs baseline: 1.2913x; 1.0291x over previous
//
#include <hip/hip_runtime.h>
#include <hip/hip_bf16.h>
#include <hip/hip_fp16.h>

// Problem constants: B=8, IN_C=64, H=W=32, NH=8, dkh=dvh=8, OUT_C=128.
//
// R16->R18 (k_attn LDS-issue reduction + exp2):
// (1) AW bias hoisted to registers: m0=((kt&1)<<4)+g*4 has only 2 values per
//     q-tile -> 128 b128 LDS reads collapse to 4 hoisted float4s.
// (2) kt-loop unrolled x2: AH (hb=kt>>1) read shared by kt pairs.
//     Main-loop LDS reads/wave: 384 -> 192.
// (3) q pre-scaled by log2(e) in k_qkv (QK, AW, AH all linear in q) ->
//     exp2 replaces mul+exp (-512 VALU/thread). Via __builtin_amdgcn_exp2f
//     (v_exp_f32); "__exp2f" name collides with glibc math.h macros (R17).
// (4) Vt stride 1032->1036 halves (8B-aligned; staging-write bank conflict
//     8-way -> 2-way-free).
// (5) k_qkv wT-prep blocks run FIRST (blk 0..15), not as a serial tail.

// ---- workspace layout (float32 element offsets) ----
constexpr int QBUF  = 0;                       // [64 bn][1024][8] f32 (q * scale * log2e)
constexpr int KVBUF = 524288;                  // [64 bn][1024][8] uint (f16x2 k|v)
constexpr int APRE  = KVBUF + 524288;          // [8][64][1024]
constexpr int XT    = APRE + 524288;           // f16 [8][1024][64] = 524288 halves
constexpr int WT    = XT + 262144;             // f16 [64][576] = 36864 halves

typedef _Float16 f16x4 __attribute__((ext_vector_type(4)));
typedef _Float16 f16x8 __attribute__((ext_vector_type(8)));
typedef float f32x4 __attribute__((ext_vector_type(4)));

__device__ __forceinline__ float fexp2(float x) {
#if defined(__has_builtin) && __has_builtin(__builtin_amdgcn_exp2f)
    return __builtin_amdgcn_exp2f(x);      // v_exp_f32
#else
    return exp2f(x);
#endif
}

__device__ __forceinline__ float dot8(float4 a, float4 b, const float* r) {
    return a.x*r[0] + a.y*r[1] + a.z*r[2] + a.w*r[3] +
           b.x*r[4] + b.y*r[5] + b.z*r[6] + b.w*r[7];
}

__device__ __forceinline__ f32x4 mfma16x16x32f16(f16x8 a, f16x8 b, f32x4 c) {
    return __builtin_amdgcn_mfma_f32_16x16x32_f16(a, b, c, 0, 0, 0);
}

__device__ __forceinline__ f32x4 mfma16x16x16f16(f16x4 a, f16x4 b, f32x4 c) {
    return __builtin_amdgcn_mfma_f32_16x16x16f16(a, b, c, 0, 0, 0);
}

union PK16 { __half2 hh; unsigned int u; };
union F16V { uint4 u; f16x8 h; };
union F16V4 { uint2 u; f16x4 h; };

// q scale: dkh^-0.5 * log2(e)  (exp(s) == exp2(s*log2e), all logit terms linear in q)
constexpr float QSCALE = 0.35355339059327373f * 1.4426950408889634f;

// ---------------------------------------------------------------------------
// Kernel 1: qkv 1x1 conv. blk 0..15 = wT prep (runs first), 16..527 = main.
// og==0 main blocks also write xT (f16, position-major).
// ---------------------------------------------------------------------------
__global__ __launch_bounds__(256) void k_qkv(
    const float* __restrict__ x,
    const float* __restrict__ wq,
    const float* __restrict__ bq,
    const float* __restrict__ wconv,
    float* __restrict__ qbuf,
    unsigned int* __restrict__ kvh,
    unsigned short* __restrict__ xt,
    __half* __restrict__ wt)
{
    int blk = blockIdx.x;
    int tid = threadIdx.x;

    if (blk < 16) {                        // wT prep: 16 blocks x 4 oc each
        int oc0 = blk * 4;
        const float* src = wconv + oc0 * 576;   // coalesced linear reads
        #pragma unroll
        for (int j = 0; j < 9; ++j) {
            int local = tid + j * 256;     // 0..2303 (= 4*576)
            float v = src[local];
            int ocr = local / 576, rem = local % 576;
            int ic = rem / 9, tap = rem % 9;
            wt[(oc0 + ocr) * 576 + tap * 64 + ic] = __float2half_rn(v);
        }
        return;
    }

    __shared__ __align__(16) float4 wl4[192];   // 12 rows x 16 float4
    __shared__ float bl[12];

    int mblk = blk - 16;
    int b = mblk >> 6, rem = mblk & 63, pc = rem >> 4, og = rem & 15;

    if (tid < 192) wl4[tid] = ((const float4*)(wq + og * 768))[tid];
    if (tid < 12)  bl[tid] = bq[og * 12 + tid];

    int p = pc * 256 + tid;                // 0..1023
    const float* xb = x + (b * 64) * 1024 + p;
    float xr[64];
    #pragma unroll
    for (int c = 0; c < 64; ++c) xr[c] = xb[c * 1024];

    __syncthreads();

    for (int pr = 0; pr < 6; ++pr) {       // channel pair (2 chains live)
        int oo = pr * 2;
        float accA = bl[oo], accB = bl[oo + 1];
        #pragma unroll
        for (int c4 = 0; c4 < 16; ++c4) {
            float4 wa = wl4[oo * 16 + c4];        // LDS broadcast
            float4 wb = wl4[(oo + 1) * 16 + c4];
            accA = fmaf(wa.x, xr[c4 * 4 + 0], accA);
            accA = fmaf(wa.y, xr[c4 * 4 + 1], accA);
            accA = fmaf(wa.z, xr[c4 * 4 + 2], accA);
            accA = fmaf(wa.w, xr[c4 * 4 + 3], accA);
            accB = fmaf(wb.x, xr[c4 * 4 + 0], accB);
            accB = fmaf(wb.y, xr[c4 * 4 + 1], accB);
            accB = fmaf(wb.z, xr[c4 * 4 + 2], accB);
            accB = fmaf(wb.w, xr[c4 * 4 + 3], accB);
        }
        int o = og * 12 + oo;              // even; pair never straddles q/k/v
        if (o < 64) {
            float2 qv = make_float2(accA * QSCALE, accB * QSCALE);
            *(float2*)(qbuf + ((b * 8 + (o >> 3)) * 1024 + p) * 8 + (o & 7)) = qv;
        } else {
            PK16 pk;
            pk.hh = __floats2half2_rn(accA, accB);
            int idx;
            if (o < 128) {
                int kk = o - 64;
                idx = ((b * 8 + (kk >> 3)) * 1024 + p) * 8 + ((kk & 7) >> 1);
            } else {
                int vv = o - 128;
                idx = ((b * 8 + (vv >> 3)) * 1024 + p) * 8 + 4 + ((vv & 7) >> 1);
            }
            kvh[idx] = pk.u;
        }
    }

    if (og == 0) {                         // xT: f16 [b][p][64 ic]
        unsigned int px[32];
        #pragma unroll
        for (int i = 0; i < 32; ++i) {
            PK16 pk;
            pk.hh = __floats2half2_rn(xr[2 * i], xr[2 * i + 1]);
            px[i] = pk.u;
        }
        uint4* dst = (uint4*)(xt + ((size_t)b * 1024 + p) * 64);
        #pragma unroll
        for (int j = 0; j < 8; ++j)
            dst[j] = make_uint4(px[4 * j], px[4 * j + 1], px[4 * j + 2], px[4 * j + 3]);
    }
}

// ---------------------------------------------------------------------------
// Kernel 2: attention via MFMA. grid = 64(bn) x 8(query chunk of 128) = 512.
// 4 waves x 32 queries; all 1024 keys staged once:
//   Kl [1024][8]h linear, Vt [9][1036]h transposed (row 8 = ones -> l-sum),
//   AWS [128][36]f32 / AHS [128][36]h: rel-bias tables PRE-SHIFTED by query
//   position (index = key&31 / key>>5). AW hoisted to 4 registers (only 2
//   distinct m0 per q-tile); kt unrolled x2 to share the AH read.
// All logits carry log2e (q pre-scaled) -> exp2.
// ---------------------------------------------------------------------------
__global__ __launch_bounds__(256) void k_attn(
    const float* __restrict__ qbuf,
    const unsigned int* __restrict__ kvh,
    const float* __restrict__ relw,
    const float* __restrict__ relh,
    float* __restrict__ apre)
{
    __shared__ __align__(16) unsigned char smem[62688];
    unsigned short* Vt  = (unsigned short*)smem;            // [9][1036] halves
    unsigned short* Kl  = (unsigned short*)(smem + 18656);  // [1024][8] halves
    float*          AWS = (float*)(smem + 35040);           // [128][36] f32
    _Float16*       AHS = (_Float16*)(smem + 53472);        // [128][36] f16

    int tid = threadIdx.x;
    int lane = tid & 63, wv = tid >> 6;
    int bn = blockIdx.x >> 3, qc = blockIdx.x & 7;
    int b = bn >> 3, nh = bn & 7;

    // ---- stage K (linear) + V (transposed pairs) ----
    {
        const uint4* kvsrc = (const uint4*)kvh + bn * 2048;  // [pos*2 + {k,v}]
        int p0 = tid * 4;
        #pragma unroll
        for (int pp = 0; pp < 2; ++pp) {
            int pa = p0 + pp * 2;
            uint4 ka = kvsrc[pa * 2 + 0], va = kvsrc[pa * 2 + 1];
            uint4 kb = kvsrc[pa * 2 + 2], vb = kvsrc[pa * 2 + 3];
            *(uint4*)(Kl + pa * 8) = ka;
            *(uint4*)(Kl + pa * 8 + 8) = kb;
            const unsigned short* ha = (const unsigned short*)&va;
            const unsigned short* hb = (const unsigned short*)&vb;
            #pragma unroll
            for (int dv = 0; dv < 8; ++dv) {
                unsigned int pk = (unsigned int)ha[dv] | ((unsigned int)hb[dv] << 16);
                *(unsigned int*)(Vt + dv * 1036 + pa) = pk;
            }
        }
        // ones row (dv==8): acc2 row 8 accumulates sum(P) = denominator
        *(unsigned long long*)(Vt + 8 * 1036 + tid * 4) = 0x3C003C003C003C00ull;
    }

    // ---- pre-shifted bias tables (log2e already inside qbuf) ----
    {
        int qloc = tid >> 1, hh = (tid & 1) * 16;
        int q = qc * 128 + qloc;
        const float* qp = qbuf + (bn * 1024 + q) * 8;
        float4 qa = *(const float4*)qp, qb2 = *(const float4*)(qp + 4);
        int wq = q & 31, hq = q >> 5;
        #pragma unroll
        for (int m = 0; m < 16; ++m)
            AWS[qloc * 36 + hh + m] = dot8(qa, qb2, relw + (hh + m + 31 - wq) * 8);
        #pragma unroll
        for (int m = 0; m < 16; ++m)
            AHS[qloc * 36 + hh + m] =
                (_Float16)dot8(qa, qb2, relh + (hh + m + 31 - hq) * 8);
    }

    // ---- per-wave Q fragments (2 q-tiles of 16 queries) ----
    int r = lane & 15, g = lane >> 4;
    int qrow0 = wv * 32;
    f16x8 qf[2];
    #pragma unroll
    for (int qt = 0; qt < 2; ++qt) {
        f16x8 v = {0, 0, 0, 0, 0, 0, 0, 0};
        if (g == 0) {
            const float* qp = qbuf + (bn * 1024 + qc * 128 + qrow0 + qt * 16 + r) * 8;
            float4 a = *(const float4*)qp;
            float4 c = *(const float4*)(qp + 4);
            v[0] = (_Float16)a.x; v[1] = (_Float16)a.y;
            v[2] = (_Float16)a.z; v[3] = (_Float16)a.w;
            v[4] = (_Float16)c.x; v[5] = (_Float16)c.y;
            v[6] = (_Float16)c.z; v[7] = (_Float16)c.w;
        }
        qf[qt] = v;
    }

    __syncthreads();

    // ---- hoist AW: only two m0 values per q-tile (kt parity) ----
    float4 awE[2], awO[2];
    #pragma unroll
    for (int qt = 0; qt < 2; ++qt) {
        int qrow = qrow0 + qt * 16 + r;
        awE[qt] = *(const float4*)(AWS + qrow * 36 + g * 4);
        awO[qt] = *(const float4*)(AWS + qrow * 36 + 16 + g * 4);
    }

    f32x4 acc2[2] = {{0.f, 0.f, 0.f, 0.f}, {0.f, 0.f, 0.f, 0.f}};
    const f32x4 zero = {0.f, 0.f, 0.f, 0.f};

    #pragma unroll 2
    for (int ktp = 0; ktp < 32; ++ktp) {
        int kt0 = ktp * 2;
        F16V kf0, kf1; F16V4 vt0, vt1;
        kf0.u = *(const uint4*)(Kl + (kt0 * 16 + r) * 8);
        kf1.u = *(const uint4*)(Kl + (kt0 * 16 + 16 + r) * 8);
        vt0.u = *(const uint2*)(Vt + r * 1036 + kt0 * 16 + g * 4);
        vt1.u = *(const uint2*)(Vt + r * 1036 + kt0 * 16 + 16 + g * 4);
        #pragma unroll
        for (int qt = 0; qt < 2; ++qt) {
            int qrow = qrow0 + qt * 16 + r;
            float ah = (float)AHS[qrow * 36 + ktp];   // shared by kt0, kt0+1
            f32x4 a1 = mfma16x16x32f16(kf0.h, qf[qt], zero);
            float e0 = fexp2(a1[0] + awE[qt].x + ah);
            float e1 = fexp2(a1[1] + awE[qt].y + ah);
            float e2 = fexp2(a1[2] + awE[qt].z + ah);
            float e3 = fexp2(a1[3] + awE[qt].w + ah);
            f16x4 pf;
            pf[0] = (_Float16)e0; pf[1] = (_Float16)e1;
            pf[2] = (_Float16)e2; pf[3] = (_Float16)e3;
            acc2[qt] = mfma16x16x16f16(vt0.h, pf, acc2[qt]);

            f32x4 a2 = mfma16x16x32f16(kf1.h, qf[qt], zero);
            float o0 = fexp2(a2[0] + awO[qt].x + ah);
            float o1 = fexp2(a2[1] + awO[qt].y + ah);
            float o2 = fexp2(a2[2] + awO[qt].z + ah);
            float o3 = fexp2(a2[3] + awO[qt].w + ah);
            f16x4 pg;
            pg[0] = (_Float16)o0; pg[1] = (_Float16)o1;
            pg[2] = (_Float16)o2; pg[3] = (_Float16)o3;
            acc2[qt] = mfma16x16x16f16(vt1.h, pg, acc2[qt]);
        }
    }

    // ---- epilogue: l = acc2 row 8 (lane 32+r, elem 0); scale + store ----
    #pragma unroll
    for (int qt = 0; qt < 2; ++qt) {
        float lsum = __shfl(acc2[qt][0], 32 + r, 64);
        float inv = 1.0f / lsum;
        if (g < 2) {
            int qglob = qc * 128 + qrow0 + qt * 16 + r;
            float* ap = apre + (b * 64 + nh * 8 + g * 4) * 1024 + qglob;
            ap[0]    = acc2[qt][0] * inv;
            ap[1024] = acc2[qt][1] * inv;
            ap[2048] = acc2[qt][2] * inv;
            ap[3072] = acc2[qt][3] * inv;
        }
    }
}

// ---------------------------------------------------------------------------
// Kernel 3: fused output. grid = 384 blocks:
//   blk < 128: 3x3 conv via MFMA implicit GEMM (unchanged from R14).
//   blk >= 128: attn 1x1 proj.
// ---------------------------------------------------------------------------
__global__ __launch_bounds__(256) void k_out(
    const unsigned short* __restrict__ xt,
    const unsigned short* __restrict__ wt,
    const float* __restrict__ bconv,
    const float* __restrict__ wattn,
    const float* __restrict__ battn,
    const float* __restrict__ apre,
    float* __restrict__ out)
{
    __shared__ __align__(16) float smem[4352];
    int blk = blockIdx.x;
    int tid = threadIdx.x;

    if (blk < 128) {
        int b = blk >> 4;
        int r0 = (blk & 15) * 2;           // image rows r0, r0+1
        int p0 = r0 * 32;
        int lane = tid & 63, wv = tid >> 6;
        int lr = lane & 15, lk = lane >> 4;
        int n0 = wv * 16;                  // this wave's oc base

        // ---- B fragments: B[k=lk*8..+7][n=n0+lr], 18 K-steps, from wT[oc][k]
        F16V bw[18];
        {
            const uint4* wp = (const uint4*)(wt + (n0 + lr) * 576 + lk * 8);
            #pragma unroll
            for (int kk = 0; kk < 18; ++kk) bw[kk].u = wp[kk * 4];
        }

        // ---- stage A halo tile: 4 rows x 34 cols x 8 slots of 16B ----
        unsigned char* ats = (unsigned char*)smem;
        {
            const uint4* xsrc = (const uint4*)xt + b * 8192;   // [1024 pos][8 slots]
            #pragma unroll
            for (int it = 0; it < 5; ++it) {
                int chunk = tid + it * 256;
                if (chunk < 1088) {
                    int s = chunk & 7, cpos = chunk >> 3;
                    int sr = cpos / 34, sc = cpos - sr * 34;
                    int ir = r0 - 1 + sr, icc = sc - 1;
                    uint4 v = make_uint4(0u, 0u, 0u, 0u);
                    if (((unsigned)ir < 32u) && ((unsigned)icc < 32u))
                        v = xsrc[(ir * 32 + icc) * 8 + s];
                    int db = ((sr * 34 + sc) * 128 + s * 16) ^ ((sc & 7) << 4);
                    *(uint4*)(ats + db) = v;
                }
            }
        }
        __syncthreads();

        f32x4 acc[4];
        #pragma unroll
        for (int mb = 0; mb < 4; ++mb) acc[mb] = f32x4{0.f, 0.f, 0.f, 0.f};

        // ---- K loop: kk = tap*2 + ic-half; A[m][k]=x[r+dr-1][c+dc-1][ic]
        #pragma unroll
        for (int kk = 0; kk < 18; ++kk) {
            const int tap = kk >> 1, h = kk & 1;
            const int dr = tap / 3, dc = tap - dr * 3;     // compile-time
            #pragma unroll
            for (int mb = 0; mb < 4; ++mb) {
                int m = mb * 16 + lr;                      // A row = lane&15
                int sr = (m >> 5) + dr, sc = (m & 31) + dc;
                int db = ((sr * 34 + sc) * 128 + h * 64 + lk * 16) ^ ((sc & 7) << 4);
                F16V av;
                av.u = *(const uint4*)(ats + db);
                acc[mb] = __builtin_amdgcn_mfma_f32_16x16x32_f16(av.h, bw[kk].h, acc[mb], 0, 0, 0);
            }
        }

        // ---- epilogue: D[row=lk*4+r + mb*16][col=n0+lr] -> LDS -> coalesced
        __syncthreads();                   // A-tile reads done; reuse smem
        #pragma unroll
        for (int mb = 0; mb < 4; ++mb) {
            #pragma unroll
            for (int rr = 0; rr < 4; ++rr)
                smem[(mb * 16 + lk * 4 + rr) * 65 + n0 + lr] = acc[mb][rr];
        }
        __syncthreads();

        int oc = tid >> 2, pq = tid & 3;
        float bia = bconv[oc];
        float* op = out + ((b * 128 + oc) * 1024) + p0 + pq * 16;
        #pragma unroll
        for (int j4 = 0; j4 < 4; ++j4) {
            int mloc = pq * 16 + j4 * 4;
            float4 o4;
            o4.x = smem[(mloc + 0) * 65 + oc] + bia;
            o4.y = smem[(mloc + 1) * 65 + oc] + bia;
            o4.z = smem[(mloc + 2) * 65 + oc] + bia;
            o4.w = smem[(mloc + 3) * 65 + oc] + bia;
            *(float4*)(op + j4 * 4) = o4;
        }
    } else {
        int pb = blk - 128;
        int b = pb >> 5, rem = pb & 31, rg = rem >> 3, og = rem & 7;
        int o0 = og * 8;
        float* wl = smem;                  // [64 c][8 g]
        for (int i = tid; i < 512; i += 256) {
            int g = i & 7, c = i >> 3;
            wl[c * 8 + g] = wattn[(o0 + g) * 64 + c];
        }
        if (tid < 8) smem[512 + tid] = battn[o0 + tid];
        __syncthreads();

        int p = rg * 256 + tid;
        float acc[8] = {0, 0, 0, 0, 0, 0, 0, 0};
        const float* ap = apre + b * 65536 + p;
        #pragma unroll 16
        for (int c = 0; c < 64; ++c) {
            float xv = ap[c * 1024];
            const float4* wv4 = (const float4*)(wl + c * 8);
            float4 wa = wv4[0], wb = wv4[1];  // broadcast
            acc[0] = fmaf(wa.x, xv, acc[0]); acc[1] = fmaf(wa.y, xv, acc[1]);
            acc[2] = fmaf(wa.z, xv, acc[2]); acc[3] = fmaf(wa.w, xv, acc[3]);
            acc[4] = fmaf(wb.x, xv, acc[4]); acc[5] = fmaf(wb.y, xv, acc[5]);
            acc[6] = fmaf(wb.z, xv, acc[6]); acc[7] = fmaf(wb.w, xv, acc[7]);
        }
        #pragma unroll
        for (int g = 0; g < 8; ++g)
            out[(b * 128 + 64 + o0 + g) * 1024 + p] = acc[g] + smem[512 + g];
    }
}

// ---------------------------------------------------------------------------
extern "C" void kernel_launch(void* const* d_in, const int* in_sizes, int n_in,
                              void* d_out, int out_size, void* d_ws, size_t ws_size,
                              hipStream_t stream)
{
    float* ws = (float*)d_ws;
    float* out = (float*)d_out;
    const float* x      = (const float*)d_in[0];
    const float* conv_w = (const float*)d_in[1];
    const float* conv_b = (const float*)d_in[2];
    const float* qkv_w  = (const float*)d_in[3];
    const float* qkv_b  = (const float*)d_in[4];
    const float* attn_w = (const float*)d_in[5];
    const float* attn_b = (const float*)d_in[6];
    const float* rel_w  = (const float*)d_in[7];
    const float* rel_h  = (const float*)d_in[8];

    k_qkv<<<528, 256, 0, stream>>>(
        x, qkv_w, qkv_b, conv_w,
        ws + QBUF, (unsigned int*)(ws + KVBUF),
        (unsigned short*)(ws + XT), (__half*)(ws + WT));
    k_attn<<<512, 256, 0, stream>>>(
        ws + QBUF, (const unsigned int*)(ws + KVBUF), rel_w, rel_h, ws + APRE);
    k_out<<<384, 256, 0, stream>>>(
        (const unsigned short*)(ws + XT), (const unsigned short*)(ws + WT),
        conv_b, attn_w, attn_b, ws + APRE, out);
}

// Round 6
// 116.064 us; speedup vs baseline: 1.3065x; 1.0118x over previous
//
#include <hip/hip_runtime.h>
#include <hip/hip_bf16.h>
#include <hip/hip_fp16.h>

// Problem constants: B=8, IN_C=64, H=W=32, NH=8, dkh=dvh=8, OUT_C=128.
//
// R18->R19 (k_attn occupancy 2->3 blocks/CU):
// AWS table dropped from LDS: each thread consumed it as only 4 hoisted
// float4s -> compute those 16 values in registers (16 dot8, from the q rows
// already loaded for the Q fragment; wq = qrow&31 since qc*128 is 32-aligned).
// LDS 62688 -> 45280 B => 3 blocks/CU (12 waves), better latency hiding for
// the ds_read -> QK-mfma -> exp2 -> cvt -> PV-mfma chain. AHS re-strided to
// [128][40] f16 (16B-aligned rows). Bias->key mapping unchanged.

// ---- workspace layout (float32 element offsets) ----
constexpr int QBUF  = 0;                       // [64 bn][1024][8] f32 (q * scale * log2e)
constexpr int KVBUF = 524288;                  // [64 bn][1024][8] uint (f16x2 k|v)
constexpr int APRE  = KVBUF + 524288;          // [8][64][1024]
constexpr int XT    = APRE + 524288;           // f16 [8][1024][64] = 524288 halves
constexpr int WT    = XT + 262144;             // f16 [64][576] = 36864 halves

typedef _Float16 f16x4 __attribute__((ext_vector_type(4)));
typedef _Float16 f16x8 __attribute__((ext_vector_type(8)));
typedef float f32x4 __attribute__((ext_vector_type(4)));

__device__ __forceinline__ float fexp2(float x) {
#if defined(__has_builtin) && __has_builtin(__builtin_amdgcn_exp2f)
    return __builtin_amdgcn_exp2f(x);      // v_exp_f32
#else
    return exp2f(x);
#endif
}

__device__ __forceinline__ float dot8(float4 a, float4 b, const float* r) {
    return a.x*r[0] + a.y*r[1] + a.z*r[2] + a.w*r[3] +
           b.x*r[4] + b.y*r[5] + b.z*r[6] + b.w*r[7];
}

__device__ __forceinline__ f32x4 mfma16x16x32f16(f16x8 a, f16x8 b, f32x4 c) {
    return __builtin_amdgcn_mfma_f32_16x16x32_f16(a, b, c, 0, 0, 0);
}

__device__ __forceinline__ f32x4 mfma16x16x16f16(f16x4 a, f16x4 b, f32x4 c) {
    return __builtin_amdgcn_mfma_f32_16x16x16f16(a, b, c, 0, 0, 0);
}

union PK16 { __half2 hh; unsigned int u; };
union F16V { uint4 u; f16x8 h; };
union F16V4 { uint2 u; f16x4 h; };

// q scale: dkh^-0.5 * log2(e)  (exp(s) == exp2(s*log2e), all logit terms linear in q)
constexpr float QSCALE = 0.35355339059327373f * 1.4426950408889634f;

// ---------------------------------------------------------------------------
// Kernel 1: qkv 1x1 conv. blk 0..15 = wT prep (runs first), 16..527 = main.
// og==0 main blocks also write xT (f16, position-major).
// ---------------------------------------------------------------------------
__global__ __launch_bounds__(256) void k_qkv(
    const float* __restrict__ x,
    const float* __restrict__ wq,
    const float* __restrict__ bq,
    const float* __restrict__ wconv,
    float* __restrict__ qbuf,
    unsigned int* __restrict__ kvh,
    unsigned short* __restrict__ xt,
    __half* __restrict__ wt)
{
    int blk = blockIdx.x;
    int tid = threadIdx.x;

    if (blk < 16) {                        // wT prep: 16 blocks x 4 oc each
        int oc0 = blk * 4;
        const float* src = wconv + oc0 * 576;   // coalesced linear reads
        #pragma unroll
        for (int j = 0; j < 9; ++j) {
            int local = tid + j * 256;     // 0..2303 (= 4*576)
            float v = src[local];
            int ocr = local / 576, rem = local % 576;
            int ic = rem / 9, tap = rem % 9;
            wt[(oc0 + ocr) * 576 + tap * 64 + ic] = __float2half_rn(v);
        }
        return;
    }

    __shared__ __align__(16) float4 wl4[192];   // 12 rows x 16 float4
    __shared__ float bl[12];

    int mblk = blk - 16;
    int b = mblk >> 6, rem = mblk & 63, pc = rem >> 4, og = rem & 15;

    if (tid < 192) wl4[tid] = ((const float4*)(wq + og * 768))[tid];
    if (tid < 12)  bl[tid] = bq[og * 12 + tid];

    int p = pc * 256 + tid;                // 0..1023
    const float* xb = x + (b * 64) * 1024 + p;
    float xr[64];
    #pragma unroll
    for (int c = 0; c < 64; ++c) xr[c] = xb[c * 1024];

    __syncthreads();

    for (int pr = 0; pr < 6; ++pr) {       // channel pair (2 chains live)
        int oo = pr * 2;
        float accA = bl[oo], accB = bl[oo + 1];
        #pragma unroll
        for (int c4 = 0; c4 < 16; ++c4) {
            float4 wa = wl4[oo * 16 + c4];        // LDS broadcast
            float4 wb = wl4[(oo + 1) * 16 + c4];
            accA = fmaf(wa.x, xr[c4 * 4 + 0], accA);
            accA = fmaf(wa.y, xr[c4 * 4 + 1], accA);
            accA = fmaf(wa.z, xr[c4 * 4 + 2], accA);
            accA = fmaf(wa.w, xr[c4 * 4 + 3], accA);
            accB = fmaf(wb.x, xr[c4 * 4 + 0], accB);
            accB = fmaf(wb.y, xr[c4 * 4 + 1], accB);
            accB = fmaf(wb.z, xr[c4 * 4 + 2], accB);
            accB = fmaf(wb.w, xr[c4 * 4 + 3], accB);
        }
        int o = og * 12 + oo;              // even; pair never straddles q/k/v
        if (o < 64) {
            float2 qv = make_float2(accA * QSCALE, accB * QSCALE);
            *(float2*)(qbuf + ((b * 8 + (o >> 3)) * 1024 + p) * 8 + (o & 7)) = qv;
        } else {
            PK16 pk;
            pk.hh = __floats2half2_rn(accA, accB);
            int idx;
            if (o < 128) {
                int kk = o - 64;
                idx = ((b * 8 + (kk >> 3)) * 1024 + p) * 8 + ((kk & 7) >> 1);
            } else {
                int vv = o - 128;
                idx = ((b * 8 + (vv >> 3)) * 1024 + p) * 8 + 4 + ((vv & 7) >> 1);
            }
            kvh[idx] = pk.u;
        }
    }

    if (og == 0) {                         // xT: f16 [b][p][64 ic]
        unsigned int px[32];
        #pragma unroll
        for (int i = 0; i < 32; ++i) {
            PK16 pk;
            pk.hh = __floats2half2_rn(xr[2 * i], xr[2 * i + 1]);
            px[i] = pk.u;
        }
        uint4* dst = (uint4*)(xt + ((size_t)b * 1024 + p) * 64);
        #pragma unroll
        for (int j = 0; j < 8; ++j)
            dst[j] = make_uint4(px[4 * j], px[4 * j + 1], px[4 * j + 2], px[4 * j + 3]);
    }
}

// ---------------------------------------------------------------------------
// Kernel 2: attention via MFMA. grid = 64(bn) x 8(query chunk of 128) = 512.
// 4 waves x 32 queries; all 1024 keys staged once:
//   Kl [1024][8]h linear, Vt [9][1036]h transposed (row 8 = ones -> l-sum),
//   AHS [128][40] f16: height-bias table PRE-SHIFTED by query (idx = key>>5).
// AW (width-bias) computed per-thread in registers: 16 dot8 from the q rows
// this thread already loads for its Q fragment (wq = qrow&31).
// All logits carry log2e (q pre-scaled) -> exp2.
// LDS 45280 B -> 3 blocks/CU.
// ---------------------------------------------------------------------------
__global__ __launch_bounds__(256) void k_attn(
    const float* __restrict__ qbuf,
    const unsigned int* __restrict__ kvh,
    const float* __restrict__ relw,
    const float* __restrict__ relh,
    float* __restrict__ apre)
{
    __shared__ __align__(16) unsigned char smem[45280];
    unsigned short* Vt  = (unsigned short*)smem;            // [9][1036] halves
    unsigned short* Kl  = (unsigned short*)(smem + 18656);  // [1024][8] halves
    _Float16*       AHS = (_Float16*)(smem + 35040);        // [128][40] f16

    int tid = threadIdx.x;
    int lane = tid & 63, wv = tid >> 6;
    int bn = blockIdx.x >> 3, qc = blockIdx.x & 7;
    int b = bn >> 3, nh = bn & 7;

    // ---- stage K (linear) + V (transposed pairs) ----
    {
        const uint4* kvsrc = (const uint4*)kvh + bn * 2048;  // [pos*2 + {k,v}]
        int p0 = tid * 4;
        #pragma unroll
        for (int pp = 0; pp < 2; ++pp) {
            int pa = p0 + pp * 2;
            uint4 ka = kvsrc[pa * 2 + 0], va = kvsrc[pa * 2 + 1];
            uint4 kb = kvsrc[pa * 2 + 2], vb = kvsrc[pa * 2 + 3];
            *(uint4*)(Kl + pa * 8) = ka;
            *(uint4*)(Kl + pa * 8 + 8) = kb;
            const unsigned short* ha = (const unsigned short*)&va;
            const unsigned short* hb = (const unsigned short*)&vb;
            #pragma unroll
            for (int dv = 0; dv < 8; ++dv) {
                unsigned int pk = (unsigned int)ha[dv] | ((unsigned int)hb[dv] << 16);
                *(unsigned int*)(Vt + dv * 1036 + pa) = pk;
            }
        }
        // ones row (dv==8): acc2 row 8 accumulates sum(P) = denominator
        *(unsigned long long*)(Vt + 8 * 1036 + tid * 4) = 0x3C003C003C003C00ull;
    }

    // ---- AHS table (height bias, pre-shifted; log2e inside qbuf) ----
    {
        int qloc = tid >> 1, hh = (tid & 1) * 16;
        int q = qc * 128 + qloc;
        const float* qp = qbuf + (bn * 1024 + q) * 8;
        float4 qa = *(const float4*)qp, qb2 = *(const float4*)(qp + 4);
        int hq = q >> 5;
        #pragma unroll
        for (int m = 0; m < 16; ++m)
            AHS[qloc * 40 + hh + m] =
                (_Float16)dot8(qa, qb2, relh + (hh + m + 31 - hq) * 8);
    }

    // ---- per-thread: q rows, Q fragments, AW bias in registers ----
    int r = lane & 15, g = lane >> 4;
    int qrow0 = wv * 32;
    f16x8 qf[2];
    float awE[2][4], awO[2][4];
    #pragma unroll
    for (int qt = 0; qt < 2; ++qt) {
        int qrow = qrow0 + qt * 16 + r;                    // 0..127
        const float* qp = qbuf + (bn * 1024 + qc * 128 + qrow) * 8;
        float4 qa = *(const float4*)qp;
        float4 qb2 = *(const float4*)(qp + 4);
        f16x8 v = {0, 0, 0, 0, 0, 0, 0, 0};
        if (g == 0) {
            v[0] = (_Float16)qa.x; v[1] = (_Float16)qa.y;
            v[2] = (_Float16)qa.z; v[3] = (_Float16)qa.w;
            v[4] = (_Float16)qb2.x; v[5] = (_Float16)qb2.y;
            v[6] = (_Float16)qb2.z; v[7] = (_Float16)qb2.w;
        }
        qf[qt] = v;
        int wq = qrow & 31;                                // qc*128 is 32-aligned
        #pragma unroll
        for (int j = 0; j < 4; ++j) {
            awE[qt][j] = dot8(qa, qb2, relw + (g * 4 + j + 31 - wq) * 8);
            awO[qt][j] = dot8(qa, qb2, relw + (16 + g * 4 + j + 31 - wq) * 8);
        }
    }

    __syncthreads();

    f32x4 acc2[2] = {{0.f, 0.f, 0.f, 0.f}, {0.f, 0.f, 0.f, 0.f}};
    const f32x4 zero = {0.f, 0.f, 0.f, 0.f};

    #pragma unroll 2
    for (int ktp = 0; ktp < 32; ++ktp) {
        int kt0 = ktp * 2;
        F16V kf0, kf1; F16V4 vt0, vt1;
        kf0.u = *(const uint4*)(Kl + (kt0 * 16 + r) * 8);
        kf1.u = *(const uint4*)(Kl + (kt0 * 16 + 16 + r) * 8);
        vt0.u = *(const uint2*)(Vt + r * 1036 + kt0 * 16 + g * 4);
        vt1.u = *(const uint2*)(Vt + r * 1036 + kt0 * 16 + 16 + g * 4);
        #pragma unroll
        for (int qt = 0; qt < 2; ++qt) {
            int qrow = qrow0 + qt * 16 + r;
            float ah = (float)AHS[qrow * 40 + ktp];   // shared by kt0, kt0+1
            f32x4 a1 = mfma16x16x32f16(kf0.h, qf[qt], zero);
            float e0 = fexp2(a1[0] + awE[qt][0] + ah);
            float e1 = fexp2(a1[1] + awE[qt][1] + ah);
            float e2 = fexp2(a1[2] + awE[qt][2] + ah);
            float e3 = fexp2(a1[3] + awE[qt][3] + ah);
            f16x4 pf;
            pf[0] = (_Float16)e0; pf[1] = (_Float16)e1;
            pf[2] = (_Float16)e2; pf[3] = (_Float16)e3;
            acc2[qt] = mfma16x16x16f16(vt0.h, pf, acc2[qt]);

            f32x4 a2 = mfma16x16x32f16(kf1.h, qf[qt], zero);
            float o0 = fexp2(a2[0] + awO[qt][0] + ah);
            float o1 = fexp2(a2[1] + awO[qt][1] + ah);
            float o2 = fexp2(a2[2] + awO[qt][2] + ah);
            float o3 = fexp2(a2[3] + awO[qt][3] + ah);
            f16x4 pg;
            pg[0] = (_Float16)o0; pg[1] = (_Float16)o1;
            pg[2] = (_Float16)o2; pg[3] = (_Float16)o3;
            acc2[qt] = mfma16x16x16f16(vt1.h, pg, acc2[qt]);
        }
    }

    // ---- epilogue: l = acc2 row 8 (lane 32+r, elem 0); scale + store ----
    #pragma unroll
    for (int qt = 0; qt < 2; ++qt) {
        float lsum = __shfl(acc2[qt][0], 32 + r, 64);
        float inv = 1.0f / lsum;
        if (g < 2) {
            int qglob = qc * 128 + qrow0 + qt * 16 + r;
            float* ap = apre + (b * 64 + nh * 8 + g * 4) * 1024 + qglob;
            ap[0]    = acc2[qt][0] * inv;
            ap[1024] = acc2[qt][1] * inv;
            ap[2048] = acc2[qt][2] * inv;
            ap[3072] = acc2[qt][3] * inv;
        }
    }
}

// ---------------------------------------------------------------------------
// Kernel 3: fused output. grid = 384 blocks:
//   blk < 128: 3x3 conv via MFMA implicit GEMM.
//   blk >= 128: attn 1x1 proj.
// ---------------------------------------------------------------------------
__global__ __launch_bounds__(256) void k_out(
    const unsigned short* __restrict__ xt,
    const unsigned short* __restrict__ wt,
    const float* __restrict__ bconv,
    const float* __restrict__ wattn,
    const float* __restrict__ battn,
    const float* __restrict__ apre,
    float* __restrict__ out)
{
    __shared__ __align__(16) float smem[4352];
    int blk = blockIdx.x;
    int tid = threadIdx.x;

    if (blk < 128) {
        int b = blk >> 4;
        int r0 = (blk & 15) * 2;           // image rows r0, r0+1
        int p0 = r0 * 32;
        int lane = tid & 63, wv = tid >> 6;
        int lr = lane & 15, lk = lane >> 4;
        int n0 = wv * 16;                  // this wave's oc base

        // ---- B fragments: B[k=lk*8..+7][n=n0+lr], 18 K-steps, from wT[oc][k]
        F16V bw[18];
        {
            const uint4* wp = (const uint4*)(wt + (n0 + lr) * 576 + lk * 8);
            #pragma unroll
            for (int kk = 0; kk < 18; ++kk) bw[kk].u = wp[kk * 4];
        }

        // ---- stage A halo tile: 4 rows x 34 cols x 8 slots of 16B ----
        unsigned char* ats = (unsigned char*)smem;
        {
            const uint4* xsrc = (const uint4*)xt + b * 8192;   // [1024 pos][8 slots]
            #pragma unroll
            for (int it = 0; it < 5; ++it) {
                int chunk = tid + it * 256;
                if (chunk < 1088) {
                    int s = chunk & 7, cpos = chunk >> 3;
                    int sr = cpos / 34, sc = cpos - sr * 34;
                    int ir = r0 - 1 + sr, icc = sc - 1;
                    uint4 v = make_uint4(0u, 0u, 0u, 0u);
                    if (((unsigned)ir < 32u) && ((unsigned)icc < 32u))
                        v = xsrc[(ir * 32 + icc) * 8 + s];
                    int db = ((sr * 34 + sc) * 128 + s * 16) ^ ((sc & 7) << 4);
                    *(uint4*)(ats + db) = v;
                }
            }
        }
        __syncthreads();

        f32x4 acc[4];
        #pragma unroll
        for (int mb = 0; mb < 4; ++mb) acc[mb] = f32x4{0.f, 0.f, 0.f, 0.f};

        // ---- K loop: kk = tap*2 + ic-half; A[m][k]=x[r+dr-1][c+dc-1][ic]
        #pragma unroll
        for (int kk = 0; kk < 18; ++kk) {
            const int tap = kk >> 1, h = kk & 1;
            const int dr = tap / 3, dc = tap - dr * 3;     // compile-time
            #pragma unroll
            for (int mb = 0; mb < 4; ++mb) {
                int m = mb * 16 + lr;                      // A row = lane&15
                int sr = (m >> 5) + dr, sc = (m & 31) + dc;
                int db = ((sr * 34 + sc) * 128 + h * 64 + lk * 16) ^ ((sc & 7) << 4);
                F16V av;
                av.u = *(const uint4*)(ats + db);
                acc[mb] = __builtin_amdgcn_mfma_f32_16x16x32_f16(av.h, bw[kk].h, acc[mb], 0, 0, 0);
            }
        }

        // ---- epilogue: D[row=lk*4+r + mb*16][col=n0+lr] -> LDS -> coalesced
        __syncthreads();                   // A-tile reads done; reuse smem
        #pragma unroll
        for (int mb = 0; mb < 4; ++mb) {
            #pragma unroll
            for (int rr = 0; rr < 4; ++rr)
                smem[(mb * 16 + lk * 4 + rr) * 65 + n0 + lr] = acc[mb][rr];
        }
        __syncthreads();

        int oc = tid >> 2, pq = tid & 3;
        float bia = bconv[oc];
        float* op = out + ((b * 128 + oc) * 1024) + p0 + pq * 16;
        #pragma unroll
        for (int j4 = 0; j4 < 4; ++j4) {
            int mloc = pq * 16 + j4 * 4;
            float4 o4;
            o4.x = smem[(mloc + 0) * 65 + oc] + bia;
            o4.y = smem[(mloc + 1) * 65 + oc] + bia;
            o4.z = smem[(mloc + 2) * 65 + oc] + bia;
            o4.w = smem[(mloc + 3) * 65 + oc] + bia;
            *(float4*)(op + j4 * 4) = o4;
        }
    } else {
        int pb = blk - 128;
        int b = pb >> 5, rem = pb & 31, rg = rem >> 3, og = rem & 7;
        int o0 = og * 8;
        float* wl = smem;                  // [64 c][8 g]
        for (int i = tid; i < 512; i += 256) {
            int g = i & 7, c = i >> 3;
            wl[c * 8 + g] = wattn[(o0 + g) * 64 + c];
        }
        if (tid < 8) smem[512 + tid] = battn[o0 + tid];
        __syncthreads();

        int p = rg * 256 + tid;
        float acc[8] = {0, 0, 0, 0, 0, 0, 0, 0};
        const float* ap = apre + b * 65536 + p;
        #pragma unroll 16
        for (int c = 0; c < 64; ++c) {
            float xv = ap[c * 1024];
            const float4* wv4 = (const float4*)(wl + c * 8);
            float4 wa = wv4[0], wb = wv4[1];  // broadcast
            acc[0] = fmaf(wa.x, xv, acc[0]); acc[1] = fmaf(wa.y, xv, acc[1]);
            acc[2] = fmaf(wa.z, xv, acc[2]); acc[3] = fmaf(wa.w, xv, acc[3]);
            acc[4] = fmaf(wb.x, xv, acc[4]); acc[5] = fmaf(wb.y, xv, acc[5]);
            acc[6] = fmaf(wb.z, xv, acc[6]); acc[7] = fmaf(wb.w, xv, acc[7]);
        }
        #pragma unroll
        for (int g = 0; g < 8; ++g)
            out[(b * 128 + 64 + o0 + g) * 1024 + p] = acc[g] + smem[512 + g];
    }
}

// ---------------------------------------------------------------------------
extern "C" void kernel_launch(void* const* d_in, const int* in_sizes, int n_in,
                              void* d_out, int out_size, void* d_ws, size_t ws_size,
                              hipStream_t stream)
{
    float* ws = (float*)d_ws;
    float* out = (float*)d_out;
    const float* x      = (const float*)d_in[0];
    const float* conv_w = (const float*)d_in[1];
    const float* conv_b = (const float*)d_in[2];
    const float* qkv_w  = (const float*)d_in[3];
    const float* qkv_b  = (const float*)d_in[4];
    const float* attn_w = (const float*)d_in[5];
    const float* attn_b = (const float*)d_in[6];
    const float* rel_w  = (const float*)d_in[7];
    const float* rel_h  = (const float*)d_in[8];

    k_qkv<<<528, 256, 0, stream>>>(
        x, qkv_w, qkv_b, conv_w,
        ws + QBUF, (unsigned int*)(ws + KVBUF),
        (unsigned short*)(ws + XT), (__half*)(ws + WT));
    k_attn<<<512, 256, 0, stream>>>(
        ws + QBUF, (const unsigned int*)(ws + KVBUF), rel_w, rel_h, ws + APRE);
    k_out<<<384, 256, 0, stream>>>(
        (const unsigned short*)(ws + XT), (const unsigned short*)(ws + WT),
        conv_b, attn_w, attn_b, ws + APRE, out);
}

// Round 7
// 115.906 us; speedup vs baseline: 1.3083x; 1.0014x over previous
//
#include <hip/hip_runtime.h>
#include <hip/hip_bf16.h>
#include <hip/hip_fp16.h>

// Problem constants: B=8, IN_C=64, H=W=32, NH=8, dkh=dvh=8, OUT_C=128.
//
// R19->R20 (split-K attention):
// k_attn's inner loop is a serial ds_read->QKmfma->exp2->PVmfma chain, 32
// deep; occupancy bump (R19) barely helped -> latency-bound. No-max softmax
// is LINEAR in keys => split each (bn,qc) into 2 blocks of 512 keys:
//   grid 512->1024 (4 blocks/CU), LDS 45.3->22.8 KB, chain depth 32->16.
// Partials written unnormalized to APRE0/APRE1 + row-sums to LBUF;
// k_out proj merges: (ap0+ap1)/(l0+l1). AW-in-reg / AH pre-shift / ones-row
// denominator unchanged (kh*512 == 0 mod 32 keeps key&31 / key>>5 logic).

// ---- workspace layout (float32 element offsets) ----
constexpr int QBUF  = 0;                       // [64 bn][1024][8] f32 (q * scale * log2e)
constexpr int KVBUF = 524288;                  // [64 bn][1024][8] uint (f16x2 k|v)
constexpr int APRE0 = 1048576;                 // [8][64][1024] partial half 0
constexpr int APRE1 = 1572864;                 // [8][64][1024] partial half 1
constexpr int LBUF  = 2097152;                 // [2][64][1024] row sums
constexpr int XT    = 2228224;                 // f16 [8][1024][64] = 524288 halves
constexpr int WT    = 2490368;                 // f16 [64][576] = 36864 halves

typedef _Float16 f16x4 __attribute__((ext_vector_type(4)));
typedef _Float16 f16x8 __attribute__((ext_vector_type(8)));
typedef float f32x4 __attribute__((ext_vector_type(4)));

__device__ __forceinline__ float fexp2(float x) {
#if defined(__has_builtin) && __has_builtin(__builtin_amdgcn_exp2f)
    return __builtin_amdgcn_exp2f(x);      // v_exp_f32
#else
    return exp2f(x);
#endif
}

__device__ __forceinline__ float dot8(float4 a, float4 b, const float* r) {
    return a.x*r[0] + a.y*r[1] + a.z*r[2] + a.w*r[3] +
           b.x*r[4] + b.y*r[5] + b.z*r[6] + b.w*r[7];
}

__device__ __forceinline__ f32x4 mfma16x16x32f16(f16x8 a, f16x8 b, f32x4 c) {
    return __builtin_amdgcn_mfma_f32_16x16x32_f16(a, b, c, 0, 0, 0);
}

__device__ __forceinline__ f32x4 mfma16x16x16f16(f16x4 a, f16x4 b, f32x4 c) {
    return __builtin_amdgcn_mfma_f32_16x16x16f16(a, b, c, 0, 0, 0);
}

union PK16 { __half2 hh; unsigned int u; };
union F16V { uint4 u; f16x8 h; };
union F16V4 { uint2 u; f16x4 h; };

// q scale: dkh^-0.5 * log2(e)  (exp(s) == exp2(s*log2e), all logit terms linear in q)
constexpr float QSCALE = 0.35355339059327373f * 1.4426950408889634f;

// ---------------------------------------------------------------------------
// Kernel 1: qkv 1x1 conv. blk 0..15 = wT prep (runs first), 16..527 = main.
// og==0 main blocks also write xT (f16, position-major). (unchanged R19)
// ---------------------------------------------------------------------------
__global__ __launch_bounds__(256) void k_qkv(
    const float* __restrict__ x,
    const float* __restrict__ wq,
    const float* __restrict__ bq,
    const float* __restrict__ wconv,
    float* __restrict__ qbuf,
    unsigned int* __restrict__ kvh,
    unsigned short* __restrict__ xt,
    __half* __restrict__ wt)
{
    int blk = blockIdx.x;
    int tid = threadIdx.x;

    if (blk < 16) {                        // wT prep: 16 blocks x 4 oc each
        int oc0 = blk * 4;
        const float* src = wconv + oc0 * 576;   // coalesced linear reads
        #pragma unroll
        for (int j = 0; j < 9; ++j) {
            int local = tid + j * 256;     // 0..2303 (= 4*576)
            float v = src[local];
            int ocr = local / 576, rem = local % 576;
            int ic = rem / 9, tap = rem % 9;
            wt[(oc0 + ocr) * 576 + tap * 64 + ic] = __float2half_rn(v);
        }
        return;
    }

    __shared__ __align__(16) float4 wl4[192];   // 12 rows x 16 float4
    __shared__ float bl[12];

    int mblk = blk - 16;
    int b = mblk >> 6, rem = mblk & 63, pc = rem >> 4, og = rem & 15;

    if (tid < 192) wl4[tid] = ((const float4*)(wq + og * 768))[tid];
    if (tid < 12)  bl[tid] = bq[og * 12 + tid];

    int p = pc * 256 + tid;                // 0..1023
    const float* xb = x + (b * 64) * 1024 + p;
    float xr[64];
    #pragma unroll
    for (int c = 0; c < 64; ++c) xr[c] = xb[c * 1024];

    __syncthreads();

    for (int pr = 0; pr < 6; ++pr) {       // channel pair (2 chains live)
        int oo = pr * 2;
        float accA = bl[oo], accB = bl[oo + 1];
        #pragma unroll
        for (int c4 = 0; c4 < 16; ++c4) {
            float4 wa = wl4[oo * 16 + c4];        // LDS broadcast
            float4 wb = wl4[(oo + 1) * 16 + c4];
            accA = fmaf(wa.x, xr[c4 * 4 + 0], accA);
            accA = fmaf(wa.y, xr[c4 * 4 + 1], accA);
            accA = fmaf(wa.z, xr[c4 * 4 + 2], accA);
            accA = fmaf(wa.w, xr[c4 * 4 + 3], accA);
            accB = fmaf(wb.x, xr[c4 * 4 + 0], accB);
            accB = fmaf(wb.y, xr[c4 * 4 + 1], accB);
            accB = fmaf(wb.z, xr[c4 * 4 + 2], accB);
            accB = fmaf(wb.w, xr[c4 * 4 + 3], accB);
        }
        int o = og * 12 + oo;              // even; pair never straddles q/k/v
        if (o < 64) {
            float2 qv = make_float2(accA * QSCALE, accB * QSCALE);
            *(float2*)(qbuf + ((b * 8 + (o >> 3)) * 1024 + p) * 8 + (o & 7)) = qv;
        } else {
            PK16 pk;
            pk.hh = __floats2half2_rn(accA, accB);
            int idx;
            if (o < 128) {
                int kk = o - 64;
                idx = ((b * 8 + (kk >> 3)) * 1024 + p) * 8 + ((kk & 7) >> 1);
            } else {
                int vv = o - 128;
                idx = ((b * 8 + (vv >> 3)) * 1024 + p) * 8 + 4 + ((vv & 7) >> 1);
            }
            kvh[idx] = pk.u;
        }
    }

    if (og == 0) {                         // xT: f16 [b][p][64 ic]
        unsigned int px[32];
        #pragma unroll
        for (int i = 0; i < 32; ++i) {
            PK16 pk;
            pk.hh = __floats2half2_rn(xr[2 * i], xr[2 * i + 1]);
            px[i] = pk.u;
        }
        uint4* dst = (uint4*)(xt + ((size_t)b * 1024 + p) * 64);
        #pragma unroll
        for (int j = 0; j < 8; ++j)
            dst[j] = make_uint4(px[4 * j], px[4 * j + 1], px[4 * j + 2], px[4 * j + 3]);
    }
}

// ---------------------------------------------------------------------------
// Kernel 2: split-K attention. grid = 64(bn) x 8(qc) x 2(key half) = 1024.
// Block: 128 queries x 512 keys. LDS 22752 B:
//   Vt [9][524]h transposed (row 8 = ones -> partial l), Kl [512][8]h,
//   AHS [128][20]h pre-shifted height bias for this half (idx = kt>>1).
// AW in registers (key&31 logic; kh*512 == 0 mod 32). Outputs UNNORMALIZED
// partial acc2 -> apre0/apre1, partial l -> lbuf. k_out merges.
// ---------------------------------------------------------------------------
__global__ __launch_bounds__(256) void k_attn(
    const float* __restrict__ qbuf,
    const unsigned int* __restrict__ kvh,
    const float* __restrict__ relw,
    const float* __restrict__ relh,
    float* __restrict__ apre0,
    float* __restrict__ apre1,
    float* __restrict__ lbuf)
{
    __shared__ __align__(16) unsigned char smem[22752];
    unsigned short* Vt  = (unsigned short*)smem;            // [9][524] halves
    unsigned short* Kl  = (unsigned short*)(smem + 9440);   // [512][8] halves
    _Float16*       AHS = (_Float16*)(smem + 17632);        // [128][20] f16

    int tid = threadIdx.x;
    int lane = tid & 63, wv = tid >> 6;
    int blk = blockIdx.x;
    int kh = blk & 1, qc = (blk >> 1) & 7, bn = blk >> 4;
    int b = bn >> 3, nh = bn & 7;

    // ---- stage K (linear) + V (transposed pairs), this half's 512 keys ----
    {
        const uint4* kvsrc = (const uint4*)kvh + (bn * 1024 + kh * 512) * 2;
        int pa = tid * 2;                  // 2 keys per thread, contiguous 64B
        uint4 ka = kvsrc[pa * 2 + 0], va = kvsrc[pa * 2 + 1];
        uint4 kb = kvsrc[pa * 2 + 2], vb = kvsrc[pa * 2 + 3];
        *(uint4*)(Kl + pa * 8) = ka;
        *(uint4*)(Kl + pa * 8 + 8) = kb;
        const unsigned short* ha = (const unsigned short*)&va;
        const unsigned short* hb = (const unsigned short*)&vb;
        #pragma unroll
        for (int dv = 0; dv < 8; ++dv) {
            unsigned int pk = (unsigned int)ha[dv] | ((unsigned int)hb[dv] << 16);
            *(unsigned int*)(Vt + dv * 524 + pa) = pk;
        }
        // ones row (dv==8): acc2 row 8 accumulates partial sum(P)
        *(unsigned int*)(Vt + 8 * 524 + pa) = 0x3C003C00u;
    }

    // ---- AHS table: 16 height-bias values per q for this half ----
    {
        int qloc = tid >> 1, m0 = (tid & 1) * 8;
        int q = qc * 128 + qloc;
        const float* qp = qbuf + (bn * 1024 + q) * 8;
        float4 qa = *(const float4*)qp, qb2 = *(const float4*)(qp + 4);
        int hq = q >> 5;
        #pragma unroll
        for (int j = 0; j < 8; ++j)
            AHS[qloc * 20 + m0 + j] =
                (_Float16)dot8(qa, qb2, relh + (kh * 16 + m0 + j + 31 - hq) * 8);
    }

    // ---- per-thread: q rows, Q fragments, AW bias in registers ----
    int r = lane & 15, g = lane >> 4;
    int qrow0 = wv * 32;
    f16x8 qf[2];
    float awE[2][4], awO[2][4];
    #pragma unroll
    for (int qt = 0; qt < 2; ++qt) {
        int qrow = qrow0 + qt * 16 + r;                    // 0..127
        const float* qp = qbuf + (bn * 1024 + qc * 128 + qrow) * 8;
        float4 qa = *(const float4*)qp;
        float4 qb2 = *(const float4*)(qp + 4);
        f16x8 v = {0, 0, 0, 0, 0, 0, 0, 0};
        if (g == 0) {
            v[0] = (_Float16)qa.x; v[1] = (_Float16)qa.y;
            v[2] = (_Float16)qa.z; v[3] = (_Float16)qa.w;
            v[4] = (_Float16)qb2.x; v[5] = (_Float16)qb2.y;
            v[6] = (_Float16)qb2.z; v[7] = (_Float16)qb2.w;
        }
        qf[qt] = v;
        int wq = qrow & 31;                                // qc*128 is 32-aligned
        #pragma unroll
        for (int j = 0; j < 4; ++j) {
            awE[qt][j] = dot8(qa, qb2, relw + (g * 4 + j + 31 - wq) * 8);
            awO[qt][j] = dot8(qa, qb2, relw + (16 + g * 4 + j + 31 - wq) * 8);
        }
    }

    __syncthreads();

    f32x4 acc2[2] = {{0.f, 0.f, 0.f, 0.f}, {0.f, 0.f, 0.f, 0.f}};
    const f32x4 zero = {0.f, 0.f, 0.f, 0.f};

    #pragma unroll 2
    for (int ktp = 0; ktp < 16; ++ktp) {
        int kt0 = ktp * 2;
        F16V kf0, kf1; F16V4 vt0, vt1;
        kf0.u = *(const uint4*)(Kl + (kt0 * 16 + r) * 8);
        kf1.u = *(const uint4*)(Kl + (kt0 * 16 + 16 + r) * 8);
        vt0.u = *(const uint2*)(Vt + r * 524 + kt0 * 16 + g * 4);
        vt1.u = *(const uint2*)(Vt + r * 524 + kt0 * 16 + 16 + g * 4);
        #pragma unroll
        for (int qt = 0; qt < 2; ++qt) {
            int qrow = qrow0 + qt * 16 + r;
            float ah = (float)AHS[qrow * 20 + ktp];   // shared by kt0, kt0+1
            f32x4 a1 = mfma16x16x32f16(kf0.h, qf[qt], zero);
            float e0 = fexp2(a1[0] + awE[qt][0] + ah);
            float e1 = fexp2(a1[1] + awE[qt][1] + ah);
            float e2 = fexp2(a1[2] + awE[qt][2] + ah);
            float e3 = fexp2(a1[3] + awE[qt][3] + ah);
            f16x4 pf;
            pf[0] = (_Float16)e0; pf[1] = (_Float16)e1;
            pf[2] = (_Float16)e2; pf[3] = (_Float16)e3;
            acc2[qt] = mfma16x16x16f16(vt0.h, pf, acc2[qt]);

            f32x4 a2 = mfma16x16x32f16(kf1.h, qf[qt], zero);
            float o0 = fexp2(a2[0] + awO[qt][0] + ah);
            float o1 = fexp2(a2[1] + awO[qt][1] + ah);
            float o2 = fexp2(a2[2] + awO[qt][2] + ah);
            float o3 = fexp2(a2[3] + awO[qt][3] + ah);
            f16x4 pg;
            pg[0] = (_Float16)o0; pg[1] = (_Float16)o1;
            pg[2] = (_Float16)o2; pg[3] = (_Float16)o3;
            acc2[qt] = mfma16x16x16f16(vt1.h, pg, acc2[qt]);
        }
    }

    // ---- epilogue: UNNORMALIZED partials; l = acc2 row 8 ----
    float* aprek = kh ? apre1 : apre0;
    #pragma unroll
    for (int qt = 0; qt < 2; ++qt) {
        float lsum = __shfl(acc2[qt][0], 32 + r, 64);
        int qglob = qc * 128 + qrow0 + qt * 16 + r;
        if (g == 0)
            lbuf[(kh * 64 + bn) * 1024 + qglob] = lsum;
        if (g < 2) {
            float* ap = aprek + (b * 64 + nh * 8 + g * 4) * 1024 + qglob;
            ap[0]    = acc2[qt][0];
            ap[1024] = acc2[qt][1];
            ap[2048] = acc2[qt][2];
            ap[3072] = acc2[qt][3];
        }
    }
}

// ---------------------------------------------------------------------------
// Kernel 3: fused output. grid = 384 blocks:
//   blk < 128: 3x3 conv via MFMA implicit GEMM (unchanged).
//   blk >= 128: attn 1x1 proj, now merging split-K partials:
//     val = (ap0 + ap1) * 1/(l0 + l1).
// ---------------------------------------------------------------------------
__global__ __launch_bounds__(256) void k_out(
    const unsigned short* __restrict__ xt,
    const unsigned short* __restrict__ wt,
    const float* __restrict__ bconv,
    const float* __restrict__ wattn,
    const float* __restrict__ battn,
    const float* __restrict__ apre0,
    const float* __restrict__ apre1,
    const float* __restrict__ lbuf,
    float* __restrict__ out)
{
    __shared__ __align__(16) float smem[4352];
    int blk = blockIdx.x;
    int tid = threadIdx.x;

    if (blk < 128) {
        int b = blk >> 4;
        int r0 = (blk & 15) * 2;           // image rows r0, r0+1
        int p0 = r0 * 32;
        int lane = tid & 63, wv = tid >> 6;
        int lr = lane & 15, lk = lane >> 4;
        int n0 = wv * 16;                  // this wave's oc base

        // ---- B fragments: B[k=lk*8..+7][n=n0+lr], 18 K-steps, from wT[oc][k]
        F16V bw[18];
        {
            const uint4* wp = (const uint4*)(wt + (n0 + lr) * 576 + lk * 8);
            #pragma unroll
            for (int kk = 0; kk < 18; ++kk) bw[kk].u = wp[kk * 4];
        }

        // ---- stage A halo tile: 4 rows x 34 cols x 8 slots of 16B ----
        unsigned char* ats = (unsigned char*)smem;
        {
            const uint4* xsrc = (const uint4*)xt + b * 8192;   // [1024 pos][8 slots]
            #pragma unroll
            for (int it = 0; it < 5; ++it) {
                int chunk = tid + it * 256;
                if (chunk < 1088) {
                    int s = chunk & 7, cpos = chunk >> 3;
                    int sr = cpos / 34, sc = cpos - sr * 34;
                    int ir = r0 - 1 + sr, icc = sc - 1;
                    uint4 v = make_uint4(0u, 0u, 0u, 0u);
                    if (((unsigned)ir < 32u) && ((unsigned)icc < 32u))
                        v = xsrc[(ir * 32 + icc) * 8 + s];
                    int db = ((sr * 34 + sc) * 128 + s * 16) ^ ((sc & 7) << 4);
                    *(uint4*)(ats + db) = v;
                }
            }
        }
        __syncthreads();

        f32x4 acc[4];
        #pragma unroll
        for (int mb = 0; mb < 4; ++mb) acc[mb] = f32x4{0.f, 0.f, 0.f, 0.f};

        // ---- K loop: kk = tap*2 + ic-half; A[m][k]=x[r+dr-1][c+dc-1][ic]
        #pragma unroll
        for (int kk = 0; kk < 18; ++kk) {
            const int tap = kk >> 1, h = kk & 1;
            const int dr = tap / 3, dc = tap - dr * 3;     // compile-time
            #pragma unroll
            for (int mb = 0; mb < 4; ++mb) {
                int m = mb * 16 + lr;                      // A row = lane&15
                int sr = (m >> 5) + dr, sc = (m & 31) + dc;
                int db = ((sr * 34 + sc) * 128 + h * 64 + lk * 16) ^ ((sc & 7) << 4);
                F16V av;
                av.u = *(const uint4*)(ats + db);
                acc[mb] = __builtin_amdgcn_mfma_f32_16x16x32_f16(av.h, bw[kk].h, acc[mb], 0, 0, 0);
            }
        }

        // ---- epilogue: D[row=lk*4+r + mb*16][col=n0+lr] -> LDS -> coalesced
        __syncthreads();                   // A-tile reads done; reuse smem
        #pragma unroll
        for (int mb = 0; mb < 4; ++mb) {
            #pragma unroll
            for (int rr = 0; rr < 4; ++rr)
                smem[(mb * 16 + lk * 4 + rr) * 65 + n0 + lr] = acc[mb][rr];
        }
        __syncthreads();

        int oc = tid >> 2, pq = tid & 3;
        float bia = bconv[oc];
        float* op = out + ((b * 128 + oc) * 1024) + p0 + pq * 16;
        #pragma unroll
        for (int j4 = 0; j4 < 4; ++j4) {
            int mloc = pq * 16 + j4 * 4;
            float4 o4;
            o4.x = smem[(mloc + 0) * 65 + oc] + bia;
            o4.y = smem[(mloc + 1) * 65 + oc] + bia;
            o4.z = smem[(mloc + 2) * 65 + oc] + bia;
            o4.w = smem[(mloc + 3) * 65 + oc] + bia;
            *(float4*)(op + j4 * 4) = o4;
        }
    } else {
        int pb = blk - 128;
        int b = pb >> 5, rem = pb & 31, rg = rem >> 3, og = rem & 7;
        int o0 = og * 8;
        float* wl = smem;                  // [64 c][8 g]
        for (int i = tid; i < 512; i += 256) {
            int g = i & 7, c = i >> 3;
            wl[c * 8 + g] = wattn[(o0 + g) * 64 + c];
        }
        if (tid < 8) smem[512 + tid] = battn[o0 + tid];
        __syncthreads();

        int p = rg * 256 + tid;

        // merge factors: 1/(l0+l1) per head
        float inv[8];
        #pragma unroll
        for (int nh = 0; nh < 8; ++nh) {
            float l0 = lbuf[(b * 8 + nh) * 1024 + p];
            float l1 = lbuf[(64 + b * 8 + nh) * 1024 + p];
            inv[nh] = 1.0f / (l0 + l1);
        }

        float acc[8] = {0, 0, 0, 0, 0, 0, 0, 0};
        const float* ap0 = apre0 + b * 65536 + p;
        const float* ap1 = apre1 + b * 65536 + p;
        #pragma unroll
        for (int c = 0; c < 64; ++c) {
            float xv = (ap0[c * 1024] + ap1[c * 1024]) * inv[c >> 3];
            const float4* wv4 = (const float4*)(wl + c * 8);
            float4 wa = wv4[0], wb = wv4[1];  // broadcast
            acc[0] = fmaf(wa.x, xv, acc[0]); acc[1] = fmaf(wa.y, xv, acc[1]);
            acc[2] = fmaf(wa.z, xv, acc[2]); acc[3] = fmaf(wa.w, xv, acc[3]);
            acc[4] = fmaf(wb.x, xv, acc[4]); acc[5] = fmaf(wb.y, xv, acc[5]);
            acc[6] = fmaf(wb.z, xv, acc[6]); acc[7] = fmaf(wb.w, xv, acc[7]);
        }
        #pragma unroll
        for (int g = 0; g < 8; ++g)
            out[(b * 128 + 64 + o0 + g) * 1024 + p] = acc[g] + smem[512 + g];
    }
}

// ---------------------------------------------------------------------------
extern "C" void kernel_launch(void* const* d_in, const int* in_sizes, int n_in,
                              void* d_out, int out_size, void* d_ws, size_t ws_size,
                              hipStream_t stream)
{
    float* ws = (float*)d_ws;
    float* out = (float*)d_out;
    const float* x      = (const float*)d_in[0];
    const float* conv_w = (const float*)d_in[1];
    const float* conv_b = (const float*)d_in[2];
    const float* qkv_w  = (const float*)d_in[3];
    const float* qkv_b  = (const float*)d_in[4];
    const float* attn_w = (const float*)d_in[5];
    const float* attn_b = (const float*)d_in[6];
    const float* rel_w  = (const float*)d_in[7];
    const float* rel_h  = (const float*)d_in[8];

    k_qkv<<<528, 256, 0, stream>>>(
        x, qkv_w, qkv_b, conv_w,
        ws + QBUF, (unsigned int*)(ws + KVBUF),
        (unsigned short*)(ws + XT), (__half*)(ws + WT));
    k_attn<<<1024, 256, 0, stream>>>(
        ws + QBUF, (const unsigned int*)(ws + KVBUF), rel_w, rel_h,
        ws + APRE0, ws + APRE1, ws + LBUF);
    k_out<<<384, 256, 0, stream>>>(
        (const unsigned short*)(ws + XT), (const unsigned short*)(ws + WT),
        conv_b, attn_w, attn_b, ws + APRE0, ws + APRE1, ws + LBUF, out);
}